// Round 10
// baseline (1259.616 us; speedup 1.0000x reference)
//
#include <hip/hip_runtime.h>

#define B_ 8
#define N_ 16384
#define F_ 6
#define M_ 128
#define K_ 16
#define D_ 768

typedef unsigned short u16;
typedef unsigned int u32;
typedef __attribute__((ext_vector_type(8))) short short8;
typedef __attribute__((ext_vector_type(4))) float f32x4;

__device__ __forceinline__ u16 f2bf(float f){
  union { float f; u32 i; } v; v.f = f;
  u32 x = v.i;
  u32 r = x + 0x7FFFu + ((x >> 16) & 1u);
  return (u16)(r >> 16);
}

// ---------------- weights f32 -> bf16 (one-shot) ----------------
__global__ __launch_bounds__(256) void conv_wbig(const float* __restrict__ W1,
                                                 const float* __restrict__ W2,
                                                 const float* __restrict__ W3,
                                                 const float* __restrict__ Wn0,
                                                 const float* __restrict__ Wn1,
                                                 u16* __restrict__ dst){
  int blk = blockIdx.x;
  const float* src; int base, dbase;
  if      (blk < 512)  { src = W1;  base = blk;        dbase = 0; }
  else if (blk < 2048) { src = W2;  base = blk - 512;  dbase = 131072; }
  else if (blk < 4352) { src = W3;  base = blk - 2048; dbase = 524288; }
  else if (blk < 6656) { src = Wn0; base = blk - 4352; dbase = 1114112; }
  else                 { src = Wn1; base = blk - 6656; dbase = 1703936; }
  int i = base * 256 + threadIdx.x;
  dst[dbase + i] = f2bf(src[i]);
}

// ---------------- FPS: f32 exact, no-spill, owner-writes winner coords ----------------
#define FPT 16
__global__ __launch_bounds__(1024, 4) void fps_kernel(const float* __restrict__ coords,
                                                      float* __restrict__ cent){
#pragma clang fp contract(off)
  int b = blockIdx.x;
  int t = threadIdx.x;
  const float* cb = coords + (size_t)b * N_ * 5;
  float px[FPT], py[FPT], pz[FPT], pw[FPT], md[FPT];
#pragma unroll
  for (int j = 0; j < FPT; j++){
    int i = t + j * 1024;
    px[j] = cb[(size_t)i*5+1]; py[j] = cb[(size_t)i*5+2];
    pz[j] = cb[(size_t)i*5+3]; pw[j] = cb[(size_t)i*5+4];
    md[j] = 1e30f;
  }
  __shared__ float s_c[4];
  __shared__ float s_wv[16];
  __shared__ int s_wi[16];
  if (t == 0){
    s_c[0]=cb[1]; s_c[1]=cb[2]; s_c[2]=cb[3]; s_c[3]=cb[4];
    float* c0 = cent + (size_t)b * M_ * 4;
    c0[0]=cb[1]; c0[1]=cb[2]; c0[2]=cb[3]; c0[3]=cb[4];
  }
  __syncthreads();
  for (int step = 1; step < M_; step++){
    float cx=s_c[0], cy=s_c[1], cz=s_c[2], ct=s_c[3];
    float bv = -1.0f; int bi = 1 << 30;
#pragma unroll
    for (int j = 0; j < FPT; j++){
      float dx=px[j]-cx, dy=py[j]-cy, dz=pz[j]-cz, dw=pw[j]-ct;
      float d = ((dx*dx + dy*dy) + dz*dz) + dw*dw;   // sequential sum, contract OFF
      float m = md[j];
      m = (d < m) ? d : m;
      md[j] = m;
      if (m > bv){ bv = m; bi = t + j * 1024; }      // first-max kept (ascending idx)
    }
#pragma unroll
    for (int off = 32; off > 0; off >>= 1){
      float ov = __shfl_down(bv, off);
      int oi = __shfl_down(bi, off);
      if (ov > bv || (ov == bv && oi < bi)){ bv = ov; bi = oi; }
    }
    if ((t & 63) == 0){ s_wv[t >> 6] = bv; s_wi[t >> 6] = bi; }
    __syncthreads();
    // all threads redundantly reduce the 16 wave results (LDS broadcast reads)
    float fv = s_wv[0]; int fi = s_wi[0];
#pragma unroll
    for (int w2 = 1; w2 < 16; w2++){
      float wv = s_wv[w2]; int wi = s_wi[w2];
      if (wv > fv || (wv == fv && wi < fi)){ fv = wv; fi = wi; }
    }
    // owner thread writes winner coords from its own registers (no global load)
    if (t == (fi & 1023)){
      int jw = fi >> 10;
      float sx=px[0], sy=py[0], sz=pz[0], sw=pw[0];
#pragma unroll
      for (int q = 1; q < FPT; q++)
        if (q == jw){ sx=px[q]; sy=py[q]; sz=pz[q]; sw=pw[q]; }
      s_c[0]=sx; s_c[1]=sy; s_c[2]=sz; s_c[3]=sw;
      float* cr = cent + ((size_t)b * M_ + step) * 4;
      cr[0]=sx; cr[1]=sy; cr[2]=sz; cr[3]=sw;
    }
    __syncthreads();
  }
}

// ---------------- stable rank by centroid time; relabel early; f32 outputs ----------------
__global__ __launch_bounds__(128) void rank_scatter(const float* __restrict__ cent_fps,
                                                    float* __restrict__ cent_sorted,
                                                    float* __restrict__ out,
                                                    size_t out_elems){
  int b = blockIdx.x, m = threadIdx.x;
  __shared__ float tt[M_];
  const float* row = cent_fps + ((size_t)b * M_ + m) * 4;
  float x=row[0], y=row[1], z=row[2], w=row[3];
  tt[m] = w;
  __syncthreads();
  int rank = 0;
  for (int j = 0; j < M_; j++){
    float tj = tt[j];
    if (tj < w || (tj == w && j < m)) rank++;       // stable argsort semantics
  }
  float* dst = cent_sorted + ((size_t)b * M_ + rank) * 4;
  dst[0]=x; dst[1]=y; dst[2]=z; dst[3]=w;
  size_t co = (size_t)B_ * M_ * D_ + ((size_t)b * M_ + rank) * 4;
  if (co + 3 < out_elems){
    out[co+0]=x; out[co+1]=y; out[co+2]=z; out[co+3]=w;
  }
  size_t mo = (size_t)B_ * M_ * D_ + (size_t)B_ * M_ * 4 + (size_t)b * M_ + m;
  if (mo < out_elems) out[mo] = 1.0f;              // mask = True -> 1.0f
}

// ---------------- kNN: f32, np op order, stable-min extraction ----------------
#define KNT 512
#define KPT 32
__global__ __launch_bounds__(512) void knn_kernel(const float* __restrict__ coords,
                                                  const float* __restrict__ cent,
                                                  int* __restrict__ knn){
#pragma clang fp contract(off)
  int cm = blockIdx.x;
  int b = cm >> 7;
  const float* cb = coords + (size_t)b * N_ * 5;
  int t = threadIdx.x;
  float cx=cent[cm*4+0], cy=cent[cm*4+1], cz=cent[cm*4+2], ct=cent[cm*4+3];
  float dist[KPT];
#pragma unroll
  for (int j = 0; j < KPT; j++){
    size_t i = t + j * KNT;
    float dx=cb[i*5+1]-cx, dy=cb[i*5+2]-cy, dz=cb[i*5+3]-cz, dw=cb[i*5+4]-ct;
    float d = ((dx*dx + dy*dy) + dz*dz) + dw*dw;
    dist[j] = sqrtf(d);                            // IEEE f32 sqrt = np.sqrt(f32)
  }
  __shared__ float s_wv[8];
  __shared__ int s_wi[8];
  __shared__ int s_bi;
  for (int r = 0; r < K_; r++){
    float bv = 3e38f; int bi = 1 << 30;
#pragma unroll
    for (int j = 0; j < KPT; j++){
      int i = t + j * KNT;
      float v = dist[j];
      if (v < bv){ bv = v; bi = i; }               // first-min kept
    }
#pragma unroll
    for (int off = 32; off > 0; off >>= 1){
      float ov = __shfl_down(bv, off);
      int oi = __shfl_down(bi, off);
      if (ov < bv || (ov == bv && oi < bi)){ bv = ov; bi = oi; }
    }
    if ((t & 63) == 0){ s_wv[t >> 6] = bv; s_wi[t >> 6] = bi; }
    __syncthreads();
    if (t == 0){
      float fv = s_wv[0]; int fi = s_wi[0];
      for (int w = 1; w < 8; w++){
        float wv = s_wv[w]; int wi = s_wi[w];
        if (wv < fv || (wv == fv && wi < fi)){ fv = wv; fi = wi; }
      }
      s_bi = fi;
      knn[(size_t)cm * K_ + r] = fi & (N_ - 1);
    }
    __syncthreads();
    int wi = s_bi;
#pragma unroll
    for (int j = 0; j < KPT; j++){
      if (t + j * KNT == wi) dist[j] = 3e38f;
    }
  }
}

// ---------------- gather + layer0 (6->256, relu), f32 math -> bf16 out ----------------
__global__ __launch_bounds__(256) void gather_l0(const float* __restrict__ feat,
                                                 const int* __restrict__ knn,
                                                 const float* __restrict__ W0,
                                                 const float* __restrict__ b0,
                                                 u16* __restrict__ h1,
                                                 int rowBase){
  int lrow = blockIdx.x;
  int grow = rowBase + lrow;
  int b = grow >> 11;            // /(M*K)=2048
  int t = threadIdx.x;
  __shared__ float sf[F_];
  if (t < F_){
    int idx = knn[grow] & (N_ - 1);
    sf[t] = feat[((size_t)b * N_ + idx) * F_ + t];
  }
  __syncthreads();
  float acc = b0[t];
#pragma unroll
  for (int k = 0; k < F_; k++) acc = fmaf(sf[k], W0[k * 256 + t], acc);
  h1[(size_t)lrow * 256 + t] = f2bf(fmaxf(acc, 0.0f));
}

// ---------------- bf16 MFMA GEMM: C = act(A @ Wb + bias_f32) ----------------
// 128x128 tile, 4 waves (2x2 of 64x64), 16x16x32 bf16 MFMA, f32 accum.
// OUTF32=0: C bf16; OUTF32=1: C f32.
template<int RELU, int OUTF32>
__global__ __launch_bounds__(256) void gemm_bf16(const u16* __restrict__ A,
                                                 const u16* __restrict__ Bw,
                                                 const float* __restrict__ bias,
                                                 void* __restrict__ Cv,
                                                 int Kd, int Nd){
  __shared__ u16 As[128][40];
  __shared__ u16 Bs[128][40];
  const int t = threadIdx.x;
  const int bm = blockIdx.y << 7;
  const int bn = blockIdx.x << 7;
  const int wave = t >> 6;
  const int lane = t & 63;
  const int wm = (wave & 1) << 6;
  const int wn = (wave >> 1) << 6;
  const int lm = lane & 15;
  const int lk = (lane >> 4) << 3;
  f32x4 acc[4][4] = {};
  for (int k0 = 0; k0 < Kd; k0 += 32){
#pragma unroll
    for (int it = 0; it < 2; it++){
      int slot = t + (it << 8);
      int r = slot >> 2;
      int c = (slot & 3) << 3;
      short8 v = *(const short8*)(A + (size_t)(bm + r) * Kd + k0 + c);
      *(short8*)&As[r][c] = v;
      int kk = slot >> 4;
      int nn = (slot & 15) << 3;
      short8 w = *(const short8*)(Bw + (size_t)(k0 + kk) * Nd + bn + nn);
#pragma unroll
      for (int q = 0; q < 8; q++) Bs[nn + q][kk] = ((const u16*)&w)[q];
    }
    __syncthreads();
    short8 af[4], bfr[4];
#pragma unroll
    for (int mt = 0; mt < 4; mt++) af[mt] = *(const short8*)&As[wm + (mt << 4) + lm][lk];
#pragma unroll
    for (int nt = 0; nt < 4; nt++) bfr[nt] = *(const short8*)&Bs[wn + (nt << 4) + lm][lk];
#pragma unroll
    for (int mt = 0; mt < 4; mt++)
#pragma unroll
      for (int nt = 0; nt < 4; nt++)
        acc[mt][nt] = __builtin_amdgcn_mfma_f32_16x16x32_bf16(af[mt], bfr[nt], acc[mt][nt], 0, 0, 0);
    __syncthreads();
  }
#pragma unroll
  for (int nt = 0; nt < 4; nt++){
    int n = bn + wn + (nt << 4) + lm;
    float bia = bias[n];
#pragma unroll
    for (int mt = 0; mt < 4; mt++){
#pragma unroll
      for (int r2 = 0; r2 < 4; r2++){
        int m = bm + wm + (mt << 4) + ((lane >> 4) << 2) + r2;
        float v = acc[mt][nt][r2] + bia;
        if (RELU) v = fmaxf(v, 0.0f);
        if (OUTF32) ((float*)Cv)[(size_t)m * Nd + n] = v;
        else        ((u16*)Cv)[(size_t)m * Nd + n] = f2bf(v);
      }
    }
  }
}

// ---------------- GEMM + fused max-pool over 16-row groups (bf16 out) ----------------
__global__ __launch_bounds__(256) void gemm_pool(const u16* __restrict__ A,
                                                 const u16* __restrict__ Bw,
                                                 const float* __restrict__ bias,
                                                 u16* __restrict__ pooled,
                                                 int Kd, int Nd, int groupBase){
  __shared__ u16 As[128][40];
  __shared__ u16 Bs[128][40];
  const int t = threadIdx.x;
  const int bm = blockIdx.y << 7;
  const int bn = blockIdx.x << 7;
  const int wave = t >> 6;
  const int lane = t & 63;
  const int wm = (wave & 1) << 6;
  const int wn = (wave >> 1) << 6;
  const int lm = lane & 15;
  const int lk = (lane >> 4) << 3;
  f32x4 acc[4][4] = {};
  for (int k0 = 0; k0 < Kd; k0 += 32){
#pragma unroll
    for (int it = 0; it < 2; it++){
      int slot = t + (it << 8);
      int r = slot >> 2;
      int c = (slot & 3) << 3;
      short8 v = *(const short8*)(A + (size_t)(bm + r) * Kd + k0 + c);
      *(short8*)&As[r][c] = v;
      int kk = slot >> 4;
      int nn = (slot & 15) << 3;
      short8 w = *(const short8*)(Bw + (size_t)(k0 + kk) * Nd + bn + nn);
#pragma unroll
      for (int q = 0; q < 8; q++) Bs[nn + q][kk] = ((const u16*)&w)[q];
    }
    __syncthreads();
    short8 af[4], bfr[4];
#pragma unroll
    for (int mt = 0; mt < 4; mt++) af[mt] = *(const short8*)&As[wm + (mt << 4) + lm][lk];
#pragma unroll
    for (int nt = 0; nt < 4; nt++) bfr[nt] = *(const short8*)&Bs[wn + (nt << 4) + lm][lk];
#pragma unroll
    for (int mt = 0; mt < 4; mt++)
#pragma unroll
      for (int nt = 0; nt < 4; nt++)
        acc[mt][nt] = __builtin_amdgcn_mfma_f32_16x16x32_bf16(af[mt], bfr[nt], acc[mt][nt], 0, 0, 0);
    __syncthreads();
  }
  // each (mt) tile's 16 rows are exactly one pooling group
#pragma unroll
  for (int nt = 0; nt < 4; nt++){
    int n = bn + wn + (nt << 4) + lm;
    float bia = bias[n];
#pragma unroll
    for (int mt = 0; mt < 4; mt++){
      f32x4 a = acc[mt][nt];
      float v = fmaxf(fmaxf(a[0], a[1]), fmaxf(a[2], a[3]));
      v = fmaxf(v, __shfl_xor(v, 16));
      v = fmaxf(v, __shfl_xor(v, 32));
      if ((lane >> 4) == 0){
        int g = groupBase + (bm >> 4) + (wm >> 4) + mt;
        pooled[(size_t)g * Nd + n] = f2bf(v + bia);
      }
    }
  }
}

// ---------------- tier fallback (f32) ----------------
__global__ __launch_bounds__(256) void fill_diag(float* __restrict__ out, size_t out_elems){
  size_t i = (size_t)blockIdx.x * 256 + threadIdx.x;
  if (i >= out_elems) return;
  size_t maskStart = (size_t)B_ * M_ * D_ + (size_t)B_ * M_ * 4;
  out[i] = (i >= maskStart) ? 1.0f : 0.0f;
}

extern "C" void kernel_launch(void* const* d_in, const int* in_sizes, int n_in,
                              void* d_out, int out_size, void* d_ws, size_t ws_size,
                              hipStream_t stream){
  (void)in_sizes; (void)n_in;
  const float* coords   = (const float*)d_in[0];
  const float* features = (const float*)d_in[1];
  const float* W0 = (const float*)d_in[2];  const float* b0 = (const float*)d_in[3];
  const float* W1 = (const float*)d_in[4];  const float* b1 = (const float*)d_in[5];
  const float* W2 = (const float*)d_in[6];  const float* b2 = (const float*)d_in[7];
  const float* W3 = (const float*)d_in[8];  const float* b3 = (const float*)d_in[9];
  const float* Wn0 = (const float*)d_in[10]; const float* bn0 = (const float*)d_in[11];
  const float* Wn1 = (const float*)d_in[12]; const float* bn1 = (const float*)d_in[13];
  float* out = (float*)d_out;
  const size_t out_elems = (size_t)out_size;

  char* ws = (char*)d_ws;
  // ws layout (bytes):
  const size_t o_cent = 0;            // 16,384
  const size_t o_cntS = 16384;        // 16,384
  const size_t o_knn  = 32768;        // 65,536 -> 98,304
  const size_t o_Wb   = 131072;       // 4,587,520 bf16 W1..Wn1
  const size_t o_pool = 4718592;      // 1,572,864 bf16 [1024,768]
  const size_t o_t1   = 6291456;      // 1,572,864
  const size_t o_chunk= 7864320;      // regA (R*1536 B) + regB (R*1024 B)
  const int ROWS = B_ * M_ * K_;      // 16384

  int R = 16384;
  while (R > 128 && o_chunk + (size_t)R * 2560 > ws_size) R >>= 1;
  if (d_ws == nullptr || o_chunk + (size_t)R * 2560 > ws_size){
    fill_diag<<<(int)((out_elems + 255) / 256), 256, 0, stream>>>(out, out_elems);
    return;
  }

  float* cent_fps    = (float*)(ws + o_cent);
  float* cent_sorted = (float*)(ws + o_cntS);
  int*   knn         = (int*)(ws + o_knn);
  u16* Wb   = (u16*)(ws + o_Wb);
  u16* W1b  = Wb;               u16* W2b  = Wb + 131072;
  u16* W3b  = Wb + 524288;      u16* Wn0b = Wb + 1114112;
  u16* Wn1b = Wb + 1703936;
  u16* pooled = (u16*)(ws + o_pool);
  u16* t1     = (u16*)(ws + o_t1);
  u16* regA   = (u16*)(ws + o_chunk);                      // h1 [R,256] then h3 [R,768]
  u16* regB   = (u16*)(ws + o_chunk + (size_t)R * 1536);   // h2 [R,512]

  conv_wbig<<<8960, 256, 0, stream>>>(W1, W2, W3, Wn0, Wn1, Wb);
  fps_kernel<<<B_, 1024, 0, stream>>>(coords, cent_fps);
  rank_scatter<<<B_, 128, 0, stream>>>(cent_fps, cent_sorted, out, out_elems);
  knn_kernel<<<B_ * M_, KNT, 0, stream>>>(coords, cent_sorted, knn);

  for (int rowBase = 0; rowBase < ROWS; rowBase += R){
    gather_l0<<<R, 256, 0, stream>>>(features, knn, W0, b0, regA, rowBase);
    gemm_bf16<1,0><<<dim3(4, R / 128), 256, 0, stream>>>(regA, W1b, b1, regB, 256, 512);
    gemm_bf16<1,0><<<dim3(6, R / 128), 256, 0, stream>>>(regB, W2b, b2, regA, 512, 768);
    gemm_pool<<<dim3(6, R / 128), 256, 0, stream>>>(regA, W3b, b3, pooled, 768, 768, rowBase >> 4);
  }

  gemm_bf16<1,0><<<dim3(6, (B_ * M_) / 128), 256, 0, stream>>>(pooled, Wn0b, bn0, t1, 768, 768);
  gemm_bf16<0,1><<<dim3(6, (B_ * M_) / 128), 256, 0, stream>>>(t1, Wn1b, bn1, out, 768, 768);
}

// Round 11
// 884.488 us; speedup vs baseline: 1.4241x; 1.4241x over previous
//
#include <hip/hip_runtime.h>

#define B_ 8
#define N_ 16384
#define F_ 6
#define M_ 128
#define K_ 16
#define D_ 768

typedef unsigned short u16;
typedef unsigned int u32;
typedef __attribute__((ext_vector_type(8))) short short8;
typedef __attribute__((ext_vector_type(4))) float f32x4;

__device__ __forceinline__ u16 f2bf(float f){
  union { float f; u32 i; } v; v.f = f;
  u32 x = v.i;
  u32 r = x + 0x7FFFu + ((x >> 16) & 1u);
  return (u16)(r >> 16);
}

// ---------------- weights f32 -> bf16 (one-shot) ----------------
__global__ __launch_bounds__(256) void conv_wbig(const float* __restrict__ W1,
                                                 const float* __restrict__ W2,
                                                 const float* __restrict__ W3,
                                                 const float* __restrict__ Wn0,
                                                 const float* __restrict__ Wn1,
                                                 u16* __restrict__ dst){
  int blk = blockIdx.x;
  const float* src; int base, dbase;
  if      (blk < 512)  { src = W1;  base = blk;        dbase = 0; }
  else if (blk < 2048) { src = W2;  base = blk - 512;  dbase = 131072; }
  else if (blk < 4352) { src = W3;  base = blk - 2048; dbase = 524288; }
  else if (blk < 6656) { src = Wn0; base = blk - 4352; dbase = 1114112; }
  else                 { src = Wn1; base = blk - 6656; dbase = 1703936; }
  int i = base * 256 + threadIdx.x;
  dst[dbase + i] = f2bf(src[i]);
}

// ---------------- FPS: f32 exact; xy in LDS, z/w/md in regs -> no spill ----------------
// 8 blocks (1/batch), 1024 thr. Live regs ~60 < 64 cap. 128KB LDS (gfx950: 160KB/WG).
#define FPT 16
__global__ __launch_bounds__(1024) void fps_kernel(const float* __restrict__ coords,
                                                   float* __restrict__ cent){
#pragma clang fp contract(off)
  __shared__ float2 sxy[N_];          // 131072 B
  __shared__ float s_c[4];
  __shared__ float s_wv[16];
  __shared__ int s_wi[16];
  int b = blockIdx.x;
  int t = threadIdx.x;
  const float* cb = coords + (size_t)b * N_ * 5;
  float pz[FPT], pw[FPT], md[FPT];
#pragma unroll
  for (int j = 0; j < FPT; j++){
    int i = t + (j << 10);
    float2 xy;
    xy.x = cb[(size_t)i*5+1];
    xy.y = cb[(size_t)i*5+2];
    sxy[i] = xy;
    pz[j] = cb[(size_t)i*5+3];
    pw[j] = cb[(size_t)i*5+4];
    md[j] = 1e30f;
  }
  if (t == 0){
    s_c[0]=cb[1]; s_c[1]=cb[2]; s_c[2]=cb[3]; s_c[3]=cb[4];
    float* c0 = cent + (size_t)b * M_ * 4;
    c0[0]=cb[1]; c0[1]=cb[2]; c0[2]=cb[3]; c0[3]=cb[4];
  }
  __syncthreads();
  for (int step = 1; step < M_; step++){
    float cx=s_c[0], cy=s_c[1], cz=s_c[2], ct=s_c[3];
    float bv = -1.0f; int bi = 1 << 30;
#pragma unroll
    for (int j = 0; j < FPT; j++){
      int i = t + (j << 10);
      float2 xy = sxy[i];
      float dx=xy.x-cx, dy=xy.y-cy, dz=pz[j]-cz, dw=pw[j]-ct;
      float d = ((dx*dx + dy*dy) + dz*dz) + dw*dw;   // sequential sum, contract OFF
      float m = md[j];
      m = (d < m) ? d : m;
      md[j] = m;
      if (m > bv){ bv = m; bi = i; }                 // first-max kept (ascending idx)
    }
#pragma unroll
    for (int off = 32; off > 0; off >>= 1){
      float ov = __shfl_down(bv, off);
      int oi = __shfl_down(bi, off);
      if (ov > bv || (ov == bv && oi < bi)){ bv = ov; bi = oi; }
    }
    if ((t & 63) == 0){ s_wv[t >> 6] = bv; s_wi[t >> 6] = bi; }
    __syncthreads();
    // all threads redundantly reduce the 16 wave results (LDS broadcast reads)
    float fv = s_wv[0]; int fi = s_wi[0];
#pragma unroll
    for (int w2 = 1; w2 < 16; w2++){
      float wv = s_wv[w2]; int wi = s_wi[w2];
      if (wv > fv || (wv == fv && wi < fi)){ fv = wv; fi = wi; }
    }
    // owner thread supplies winner coords: z,w from its regs, x,y from LDS
    if (t == (fi & 1023)){
      int jw = fi >> 10;
      float sz = pz[0], sw = pw[0];
#pragma unroll
      for (int q = 1; q < FPT; q++)
        if (q == jw){ sz = pz[q]; sw = pw[q]; }
      float2 xy = sxy[fi];
      s_c[0]=xy.x; s_c[1]=xy.y; s_c[2]=sz; s_c[3]=sw;
      float* cr = cent + ((size_t)b * M_ + step) * 4;
      cr[0]=xy.x; cr[1]=xy.y; cr[2]=sz; cr[3]=sw;
    }
    __syncthreads();
  }
}

// ---------------- stable rank by centroid time; relabel early; f32 outputs ----------------
__global__ __launch_bounds__(128) void rank_scatter(const float* __restrict__ cent_fps,
                                                    float* __restrict__ cent_sorted,
                                                    float* __restrict__ out,
                                                    size_t out_elems){
  int b = blockIdx.x, m = threadIdx.x;
  __shared__ float tt[M_];
  const float* row = cent_fps + ((size_t)b * M_ + m) * 4;
  float x=row[0], y=row[1], z=row[2], w=row[3];
  tt[m] = w;
  __syncthreads();
  int rank = 0;
  for (int j = 0; j < M_; j++){
    float tj = tt[j];
    if (tj < w || (tj == w && j < m)) rank++;       // stable argsort semantics
  }
  float* dst = cent_sorted + ((size_t)b * M_ + rank) * 4;
  dst[0]=x; dst[1]=y; dst[2]=z; dst[3]=w;
  size_t co = (size_t)B_ * M_ * D_ + ((size_t)b * M_ + rank) * 4;
  if (co + 3 < out_elems){
    out[co+0]=x; out[co+1]=y; out[co+2]=z; out[co+3]=w;
  }
  size_t mo = (size_t)B_ * M_ * D_ + (size_t)B_ * M_ * 4 + (size_t)b * M_ + m;
  if (mo < out_elems) out[mo] = 1.0f;              // mask = True -> 1.0f
}

// ---------------- kNN: f32, np op order, stable-min extraction ----------------
#define KNT 512
#define KPT 32
__global__ __launch_bounds__(512) void knn_kernel(const float* __restrict__ coords,
                                                  const float* __restrict__ cent,
                                                  int* __restrict__ knn){
#pragma clang fp contract(off)
  int cm = blockIdx.x;
  int b = cm >> 7;
  const float* cb = coords + (size_t)b * N_ * 5;
  int t = threadIdx.x;
  float cx=cent[cm*4+0], cy=cent[cm*4+1], cz=cent[cm*4+2], ct=cent[cm*4+3];
  float dist[KPT];
#pragma unroll
  for (int j = 0; j < KPT; j++){
    size_t i = t + j * KNT;
    float dx=cb[i*5+1]-cx, dy=cb[i*5+2]-cy, dz=cb[i*5+3]-cz, dw=cb[i*5+4]-ct;
    float d = ((dx*dx + dy*dy) + dz*dz) + dw*dw;
    dist[j] = sqrtf(d);                            // IEEE f32 sqrt = np.sqrt(f32)
  }
  __shared__ float s_wv[8];
  __shared__ int s_wi[8];
  __shared__ int s_bi;
  for (int r = 0; r < K_; r++){
    float bv = 3e38f; int bi = 1 << 30;
#pragma unroll
    for (int j = 0; j < KPT; j++){
      int i = t + j * KNT;
      float v = dist[j];
      if (v < bv){ bv = v; bi = i; }               // first-min kept
    }
#pragma unroll
    for (int off = 32; off > 0; off >>= 1){
      float ov = __shfl_down(bv, off);
      int oi = __shfl_down(bi, off);
      if (ov < bv || (ov == bv && oi < bi)){ bv = ov; bi = oi; }
    }
    if ((t & 63) == 0){ s_wv[t >> 6] = bv; s_wi[t >> 6] = bi; }
    __syncthreads();
    if (t == 0){
      float fv = s_wv[0]; int fi = s_wi[0];
      for (int w = 1; w < 8; w++){
        float wv = s_wv[w]; int wi = s_wi[w];
        if (wv < fv || (wv == fv && wi < fi)){ fv = wv; fi = wi; }
      }
      s_bi = fi;
      knn[(size_t)cm * K_ + r] = fi & (N_ - 1);
    }
    __syncthreads();
    int wi = s_bi;
#pragma unroll
    for (int j = 0; j < KPT; j++){
      if (t + j * KNT == wi) dist[j] = 3e38f;
    }
  }
}

// ---------------- gather + layer0 (6->256, relu), f32 math -> bf16 out ----------------
__global__ __launch_bounds__(256) void gather_l0(const float* __restrict__ feat,
                                                 const int* __restrict__ knn,
                                                 const float* __restrict__ W0,
                                                 const float* __restrict__ b0,
                                                 u16* __restrict__ h1,
                                                 int rowBase){
  int lrow = blockIdx.x;
  int grow = rowBase + lrow;
  int b = grow >> 11;            // /(M*K)=2048
  int t = threadIdx.x;
  __shared__ float sf[F_];
  if (t < F_){
    int idx = knn[grow] & (N_ - 1);
    sf[t] = feat[((size_t)b * N_ + idx) * F_ + t];
  }
  __syncthreads();
  float acc = b0[t];
#pragma unroll
  for (int k = 0; k < F_; k++) acc = fmaf(sf[k], W0[k * 256 + t], acc);
  h1[(size_t)lrow * 256 + t] = f2bf(fmaxf(acc, 0.0f));
}

// ---------------- bf16 MFMA GEMM: C = act(A @ Wb + bias_f32) ----------------
// 128x128 tile, 4 waves (2x2 of 64x64), 16x16x32 bf16 MFMA, f32 accum.
// OUTF32=0: C bf16; OUTF32=1: C f32.
template<int RELU, int OUTF32>
__global__ __launch_bounds__(256) void gemm_bf16(const u16* __restrict__ A,
                                                 const u16* __restrict__ Bw,
                                                 const float* __restrict__ bias,
                                                 void* __restrict__ Cv,
                                                 int Kd, int Nd){
  __shared__ u16 As[128][40];
  __shared__ u16 Bs[128][40];
  const int t = threadIdx.x;
  const int bm = blockIdx.y << 7;
  const int bn = blockIdx.x << 7;
  const int wave = t >> 6;
  const int lane = t & 63;
  const int wm = (wave & 1) << 6;
  const int wn = (wave >> 1) << 6;
  const int lm = lane & 15;
  const int lk = (lane >> 4) << 3;
  f32x4 acc[4][4] = {};
  for (int k0 = 0; k0 < Kd; k0 += 32){
#pragma unroll
    for (int it = 0; it < 2; it++){
      int slot = t + (it << 8);
      int r = slot >> 2;
      int c = (slot & 3) << 3;
      short8 v = *(const short8*)(A + (size_t)(bm + r) * Kd + k0 + c);
      *(short8*)&As[r][c] = v;
      int kk = slot >> 4;
      int nn = (slot & 15) << 3;
      short8 w = *(const short8*)(Bw + (size_t)(k0 + kk) * Nd + bn + nn);
#pragma unroll
      for (int q = 0; q < 8; q++) Bs[nn + q][kk] = ((const u16*)&w)[q];
    }
    __syncthreads();
    short8 af[4], bfr[4];
#pragma unroll
    for (int mt = 0; mt < 4; mt++) af[mt] = *(const short8*)&As[wm + (mt << 4) + lm][lk];
#pragma unroll
    for (int nt = 0; nt < 4; nt++) bfr[nt] = *(const short8*)&Bs[wn + (nt << 4) + lm][lk];
#pragma unroll
    for (int mt = 0; mt < 4; mt++)
#pragma unroll
      for (int nt = 0; nt < 4; nt++)
        acc[mt][nt] = __builtin_amdgcn_mfma_f32_16x16x32_bf16(af[mt], bfr[nt], acc[mt][nt], 0, 0, 0);
    __syncthreads();
  }
#pragma unroll
  for (int nt = 0; nt < 4; nt++){
    int n = bn + wn + (nt << 4) + lm;
    float bia = bias[n];
#pragma unroll
    for (int mt = 0; mt < 4; mt++){
#pragma unroll
      for (int r2 = 0; r2 < 4; r2++){
        int m = bm + wm + (mt << 4) + ((lane >> 4) << 2) + r2;
        float v = acc[mt][nt][r2] + bia;
        if (RELU) v = fmaxf(v, 0.0f);
        if (OUTF32) ((float*)Cv)[(size_t)m * Nd + n] = v;
        else        ((u16*)Cv)[(size_t)m * Nd + n] = f2bf(v);
      }
    }
  }
}

// ---------------- GEMM + fused max-pool over 16-row groups (bf16 out) ----------------
__global__ __launch_bounds__(256) void gemm_pool(const u16* __restrict__ A,
                                                 const u16* __restrict__ Bw,
                                                 const float* __restrict__ bias,
                                                 u16* __restrict__ pooled,
                                                 int Kd, int Nd, int groupBase){
  __shared__ u16 As[128][40];
  __shared__ u16 Bs[128][40];
  const int t = threadIdx.x;
  const int bm = blockIdx.y << 7;
  const int bn = blockIdx.x << 7;
  const int wave = t >> 6;
  const int lane = t & 63;
  const int wm = (wave & 1) << 6;
  const int wn = (wave >> 1) << 6;
  const int lm = lane & 15;
  const int lk = (lane >> 4) << 3;
  f32x4 acc[4][4] = {};
  for (int k0 = 0; k0 < Kd; k0 += 32){
#pragma unroll
    for (int it = 0; it < 2; it++){
      int slot = t + (it << 8);
      int r = slot >> 2;
      int c = (slot & 3) << 3;
      short8 v = *(const short8*)(A + (size_t)(bm + r) * Kd + k0 + c);
      *(short8*)&As[r][c] = v;
      int kk = slot >> 4;
      int nn = (slot & 15) << 3;
      short8 w = *(const short8*)(Bw + (size_t)(k0 + kk) * Nd + bn + nn);
#pragma unroll
      for (int q = 0; q < 8; q++) Bs[nn + q][kk] = ((const u16*)&w)[q];
    }
    __syncthreads();
    short8 af[4], bfr[4];
#pragma unroll
    for (int mt = 0; mt < 4; mt++) af[mt] = *(const short8*)&As[wm + (mt << 4) + lm][lk];
#pragma unroll
    for (int nt = 0; nt < 4; nt++) bfr[nt] = *(const short8*)&Bs[wn + (nt << 4) + lm][lk];
#pragma unroll
    for (int mt = 0; mt < 4; mt++)
#pragma unroll
      for (int nt = 0; nt < 4; nt++)
        acc[mt][nt] = __builtin_amdgcn_mfma_f32_16x16x32_bf16(af[mt], bfr[nt], acc[mt][nt], 0, 0, 0);
    __syncthreads();
  }
  // each (mt) tile's 16 rows are exactly one pooling group
#pragma unroll
  for (int nt = 0; nt < 4; nt++){
    int n = bn + wn + (nt << 4) + lm;
    float bia = bias[n];
#pragma unroll
    for (int mt = 0; mt < 4; mt++){
      f32x4 a = acc[mt][nt];
      float v = fmaxf(fmaxf(a[0], a[1]), fmaxf(a[2], a[3]));
      v = fmaxf(v, __shfl_xor(v, 16));
      v = fmaxf(v, __shfl_xor(v, 32));
      if ((lane >> 4) == 0){
        int g = groupBase + (bm >> 4) + (wm >> 4) + mt;
        pooled[(size_t)g * Nd + n] = f2bf(v + bia);
      }
    }
  }
}

// ---------------- tier fallback (f32) ----------------
__global__ __launch_bounds__(256) void fill_diag(float* __restrict__ out, size_t out_elems){
  size_t i = (size_t)blockIdx.x * 256 + threadIdx.x;
  if (i >= out_elems) return;
  size_t maskStart = (size_t)B_ * M_ * D_ + (size_t)B_ * M_ * 4;
  out[i] = (i >= maskStart) ? 1.0f : 0.0f;
}

extern "C" void kernel_launch(void* const* d_in, const int* in_sizes, int n_in,
                              void* d_out, int out_size, void* d_ws, size_t ws_size,
                              hipStream_t stream){
  (void)in_sizes; (void)n_in;
  const float* coords   = (const float*)d_in[0];
  const float* features = (const float*)d_in[1];
  const float* W0 = (const float*)d_in[2];  const float* b0 = (const float*)d_in[3];
  const float* W1 = (const float*)d_in[4];  const float* b1 = (const float*)d_in[5];
  const float* W2 = (const float*)d_in[6];  const float* b2 = (const float*)d_in[7];
  const float* W3 = (const float*)d_in[8];  const float* b3 = (const float*)d_in[9];
  const float* Wn0 = (const float*)d_in[10]; const float* bn0 = (const float*)d_in[11];
  const float* Wn1 = (const float*)d_in[12]; const float* bn1 = (const float*)d_in[13];
  float* out = (float*)d_out;
  const size_t out_elems = (size_t)out_size;

  char* ws = (char*)d_ws;
  // ws layout (bytes):
  const size_t o_cent = 0;            // 16,384
  const size_t o_cntS = 16384;        // 16,384
  const size_t o_knn  = 32768;        // 65,536 -> 98,304
  const size_t o_Wb   = 131072;       // 4,587,520 bf16 W1..Wn1
  const size_t o_pool = 4718592;      // 1,572,864 bf16 [1024,768]
  const size_t o_t1   = 6291456;      // 1,572,864
  const size_t o_chunk= 7864320;      // regA (R*1536 B) + regB (R*1024 B)
  const int ROWS = B_ * M_ * K_;      // 16384

  int R = 16384;
  while (R > 128 && o_chunk + (size_t)R * 2560 > ws_size) R >>= 1;
  if (d_ws == nullptr || o_chunk + (size_t)R * 2560 > ws_size){
    fill_diag<<<(int)((out_elems + 255) / 256), 256, 0, stream>>>(out, out_elems);
    return;
  }

  float* cent_fps    = (float*)(ws + o_cent);
  float* cent_sorted = (float*)(ws + o_cntS);
  int*   knn         = (int*)(ws + o_knn);
  u16* Wb   = (u16*)(ws + o_Wb);
  u16* W1b  = Wb;               u16* W2b  = Wb + 131072;
  u16* W3b  = Wb + 524288;      u16* Wn0b = Wb + 1114112;
  u16* Wn1b = Wb + 1703936;
  u16* pooled = (u16*)(ws + o_pool);
  u16* t1     = (u16*)(ws + o_t1);
  u16* regA   = (u16*)(ws + o_chunk);                      // h1 [R,256] then h3 [R,768]
  u16* regB   = (u16*)(ws + o_chunk + (size_t)R * 1536);   // h2 [R,512]

  conv_wbig<<<8960, 256, 0, stream>>>(W1, W2, W3, Wn0, Wn1, Wb);
  fps_kernel<<<B_, 1024, 0, stream>>>(coords, cent_fps);
  rank_scatter<<<B_, 128, 0, stream>>>(cent_fps, cent_sorted, out, out_elems);
  knn_kernel<<<B_ * M_, KNT, 0, stream>>>(coords, cent_sorted, knn);

  for (int rowBase = 0; rowBase < ROWS; rowBase += R){
    gather_l0<<<R, 256, 0, stream>>>(features, knn, W0, b0, regA, rowBase);
    gemm_bf16<1,0><<<dim3(4, R / 128), 256, 0, stream>>>(regA, W1b, b1, regB, 256, 512);
    gemm_bf16<1,0><<<dim3(6, R / 128), 256, 0, stream>>>(regB, W2b, b2, regA, 512, 768);
    gemm_pool<<<dim3(6, R / 128), 256, 0, stream>>>(regA, W3b, b3, pooled, 768, 768, rowBase >> 4);
  }

  gemm_bf16<1,0><<<dim3(6, (B_ * M_) / 128), 256, 0, stream>>>(pooled, Wn0b, bn0, t1, 768, 768);
  gemm_bf16<0,1><<<dim3(6, (B_ * M_) / 128), 256, 0, stream>>>(t1, Wn1b, bn1, out, 768, 768);
}

// Round 12
// 799.328 us; speedup vs baseline: 1.5758x; 1.1065x over previous
//
#include <hip/hip_runtime.h>

#define B_ 8
#define N_ 16384
#define F_ 6
#define M_ 128
#define K_ 16
#define D_ 768

typedef unsigned short u16;
typedef unsigned int u32;
typedef __attribute__((ext_vector_type(8))) short short8;
typedef __attribute__((ext_vector_type(4))) float f32x4;

__device__ __forceinline__ u16 f2bf(float f){
  union { float f; u32 i; } v; v.f = f;
  u32 x = v.i;
  u32 r = x + 0x7FFFu + ((x >> 16) & 1u);
  return (u16)(r >> 16);
}

// ---------------- weights f32 -> bf16 (one-shot) ----------------
__global__ __launch_bounds__(256) void conv_wbig(const float* __restrict__ W1,
                                                 const float* __restrict__ W2,
                                                 const float* __restrict__ W3,
                                                 const float* __restrict__ Wn0,
                                                 const float* __restrict__ Wn1,
                                                 u16* __restrict__ dst){
  int blk = blockIdx.x;
  const float* src; int base, dbase;
  if      (blk < 512)  { src = W1;  base = blk;        dbase = 0; }
  else if (blk < 2048) { src = W2;  base = blk - 512;  dbase = 131072; }
  else if (blk < 4352) { src = W3;  base = blk - 2048; dbase = 524288; }
  else if (blk < 6656) { src = Wn0; base = blk - 4352; dbase = 1114112; }
  else                 { src = Wn1; base = blk - 6656; dbase = 1703936; }
  int i = base * 256 + threadIdx.x;
  dst[dbase + i] = f2bf(src[i]);
}

// ---------------- FPS: one barrier/step, broadcast winner, no spill ----------------
// xy in LDS, z/w/md in regs; centroid in every thread's registers.
#define FPT 16
__global__ __launch_bounds__(1024) void fps_kernel(const float* __restrict__ coords,
                                                   float* __restrict__ cent){
#pragma clang fp contract(off)
  __shared__ float2 sxy[N_];          // 131072 B
  __shared__ float s_wv[2][16];
  __shared__ int s_wi[2][16];
  int b = blockIdx.x;
  int t = threadIdx.x;
  const float* cb = coords + (size_t)b * N_ * 5;
  float pz[FPT], pw[FPT], md[FPT];
#pragma unroll
  for (int j = 0; j < FPT; j++){
    int i = t + (j << 10);
    float2 xy;
    xy.x = cb[(size_t)i*5+1];
    xy.y = cb[(size_t)i*5+2];
    sxy[i] = xy;
    pz[j] = cb[(size_t)i*5+3];
    pw[j] = cb[(size_t)i*5+4];
    md[j] = 1e30f;
  }
  // current centroid in registers (all threads; broadcast loads)
  float cx = cb[1], cy = cb[2], cz = cb[3], ct = cb[4];
  if (t == 0){
    float* c0 = cent + (size_t)b * M_ * 4;
    c0[0]=cx; c0[1]=cy; c0[2]=cz; c0[3]=ct;
  }
  __syncthreads();
  for (int step = 1; step < M_; step++){
    float bv = -1.0f; int bi = 1 << 30;
#pragma unroll
    for (int j = 0; j < FPT; j++){
      int i = t + (j << 10);
      float2 xy = sxy[i];
      float dx=xy.x-cx, dy=xy.y-cy, dz=pz[j]-cz, dw=pw[j]-ct;
      float d = ((dx*dx + dy*dy) + dz*dz) + dw*dw;   // sequential sum, contract OFF
      float m = md[j];
      m = (d < m) ? d : m;
      md[j] = m;
      if (m > bv){ bv = m; bi = i; }                 // first-max kept (ascending idx)
    }
#pragma unroll
    for (int off = 32; off > 0; off >>= 1){
      float ov = __shfl_down(bv, off);
      int oi = __shfl_down(bi, off);
      if (ov > bv || (ov == bv && oi < bi)){ bv = ov; bi = oi; }
    }
    int par = step & 1;
    if ((t & 63) == 0){ s_wv[par][t >> 6] = bv; s_wi[par][t >> 6] = bi; }
    __syncthreads();                                  // the ONLY barrier per step
    // all threads redundantly reduce the 16 wave results (LDS broadcast reads)
    float fv = s_wv[par][0]; int fi = s_wi[par][0];
#pragma unroll
    for (int w2 = 1; w2 < 16; w2++){
      float wv = s_wv[par][w2]; int wi = s_wi[par][w2];
      if (wv > fv || (wv == fv && wi < fi)){ fv = wv; fi = wi; }
    }
    fi &= (N_ - 1);
    // winner coords: x,y from LDS mirror; z,w via uniform-address global load (L1 broadcast)
    float2 xy = sxy[fi];
    cx = xy.x; cy = xy.y;
    cz = cb[(size_t)fi*5+3];
    ct = cb[(size_t)fi*5+4];
    if (t == 0){
      float* cr = cent + ((size_t)b * M_ + step) * 4;
      cr[0]=cx; cr[1]=cy; cr[2]=cz; cr[3]=ct;
    }
    // no second barrier: s_wv double-buffered by parity; sxy read-only; md/c in regs
  }
}

// ---------------- stable rank by centroid time; relabel early; f32 outputs ----------------
__global__ __launch_bounds__(128) void rank_scatter(const float* __restrict__ cent_fps,
                                                    float* __restrict__ cent_sorted,
                                                    float* __restrict__ out,
                                                    size_t out_elems){
  int b = blockIdx.x, m = threadIdx.x;
  __shared__ float tt[M_];
  const float* row = cent_fps + ((size_t)b * M_ + m) * 4;
  float x=row[0], y=row[1], z=row[2], w=row[3];
  tt[m] = w;
  __syncthreads();
  int rank = 0;
  for (int j = 0; j < M_; j++){
    float tj = tt[j];
    if (tj < w || (tj == w && j < m)) rank++;       // stable argsort semantics
  }
  float* dst = cent_sorted + ((size_t)b * M_ + rank) * 4;
  dst[0]=x; dst[1]=y; dst[2]=z; dst[3]=w;
  size_t co = (size_t)B_ * M_ * D_ + ((size_t)b * M_ + rank) * 4;
  if (co + 3 < out_elems){
    out[co+0]=x; out[co+1]=y; out[co+2]=z; out[co+3]=w;
  }
  size_t mo = (size_t)B_ * M_ * D_ + (size_t)B_ * M_ * 4 + (size_t)b * M_ + m;
  if (mo < out_elems) out[mo] = 1.0f;              // mask = True -> 1.0f
}

// ---------------- kNN: f32, np op order, stable-min extraction ----------------
#define KNT 512
#define KPT 32
__global__ __launch_bounds__(512) void knn_kernel(const float* __restrict__ coords,
                                                  const float* __restrict__ cent,
                                                  int* __restrict__ knn){
#pragma clang fp contract(off)
  int cm = blockIdx.x;
  int b = cm >> 7;
  const float* cb = coords + (size_t)b * N_ * 5;
  int t = threadIdx.x;
  float cx=cent[cm*4+0], cy=cent[cm*4+1], cz=cent[cm*4+2], ct=cent[cm*4+3];
  float dist[KPT];
#pragma unroll
  for (int j = 0; j < KPT; j++){
    size_t i = t + j * KNT;
    float dx=cb[i*5+1]-cx, dy=cb[i*5+2]-cy, dz=cb[i*5+3]-cz, dw=cb[i*5+4]-ct;
    float d = ((dx*dx + dy*dy) + dz*dz) + dw*dw;
    dist[j] = sqrtf(d);                            // IEEE f32 sqrt = np.sqrt(f32)
  }
  __shared__ float s_wv[8];
  __shared__ int s_wi[8];
  __shared__ int s_bi;
  for (int r = 0; r < K_; r++){
    float bv = 3e38f; int bi = 1 << 30;
#pragma unroll
    for (int j = 0; j < KPT; j++){
      int i = t + j * KNT;
      float v = dist[j];
      if (v < bv){ bv = v; bi = i; }               // first-min kept
    }
#pragma unroll
    for (int off = 32; off > 0; off >>= 1){
      float ov = __shfl_down(bv, off);
      int oi = __shfl_down(bi, off);
      if (ov < bv || (ov == bv && oi < bi)){ bv = ov; bi = oi; }
    }
    if ((t & 63) == 0){ s_wv[t >> 6] = bv; s_wi[t >> 6] = bi; }
    __syncthreads();
    if (t == 0){
      float fv = s_wv[0]; int fi = s_wi[0];
      for (int w = 1; w < 8; w++){
        float wv = s_wv[w]; int wi = s_wi[w];
        if (wv < fv || (wv == fv && wi < fi)){ fv = wv; fi = wi; }
      }
      s_bi = fi;
      knn[(size_t)cm * K_ + r] = fi & (N_ - 1);
    }
    __syncthreads();
    int wi = s_bi;
#pragma unroll
    for (int j = 0; j < KPT; j++){
      if (t + j * KNT == wi) dist[j] = 3e38f;
    }
  }
}

// ---------------- gather + layer0 (6->256, relu), f32 math -> bf16 out ----------------
__global__ __launch_bounds__(256) void gather_l0(const float* __restrict__ feat,
                                                 const int* __restrict__ knn,
                                                 const float* __restrict__ W0,
                                                 const float* __restrict__ b0,
                                                 u16* __restrict__ h1,
                                                 int rowBase){
  int lrow = blockIdx.x;
  int grow = rowBase + lrow;
  int b = grow >> 11;            // /(M*K)=2048
  int t = threadIdx.x;
  __shared__ float sf[F_];
  if (t < F_){
    int idx = knn[grow] & (N_ - 1);
    sf[t] = feat[((size_t)b * N_ + idx) * F_ + t];
  }
  __syncthreads();
  float acc = b0[t];
#pragma unroll
  for (int k = 0; k < F_; k++) acc = fmaf(sf[k], W0[k * 256 + t], acc);
  h1[(size_t)lrow * 256 + t] = f2bf(fmaxf(acc, 0.0f));
}

// ---------------- bf16 MFMA GEMM (128x128 tile): C = act(A @ Wb + bias) ----------------
template<int RELU, int OUTF32>
__global__ __launch_bounds__(256) void gemm_bf16(const u16* __restrict__ A,
                                                 const u16* __restrict__ Bw,
                                                 const float* __restrict__ bias,
                                                 void* __restrict__ Cv,
                                                 int Kd, int Nd){
  __shared__ u16 As[128][40];
  __shared__ u16 Bs[128][40];
  const int t = threadIdx.x;
  const int bm = blockIdx.y << 7;
  const int bn = blockIdx.x << 7;
  const int wave = t >> 6;
  const int lane = t & 63;
  const int wm = (wave & 1) << 6;
  const int wn = (wave >> 1) << 6;
  const int lm = lane & 15;
  const int lk = (lane >> 4) << 3;
  f32x4 acc[4][4] = {};
  for (int k0 = 0; k0 < Kd; k0 += 32){
#pragma unroll
    for (int it = 0; it < 2; it++){
      int slot = t + (it << 8);
      int r = slot >> 2;
      int c = (slot & 3) << 3;
      short8 v = *(const short8*)(A + (size_t)(bm + r) * Kd + k0 + c);
      *(short8*)&As[r][c] = v;
      int kk = slot >> 4;
      int nn = (slot & 15) << 3;
      short8 w = *(const short8*)(Bw + (size_t)(k0 + kk) * Nd + bn + nn);
#pragma unroll
      for (int q = 0; q < 8; q++) Bs[nn + q][kk] = ((const u16*)&w)[q];
    }
    __syncthreads();
    short8 af[4], bfr[4];
#pragma unroll
    for (int mt = 0; mt < 4; mt++) af[mt] = *(const short8*)&As[wm + (mt << 4) + lm][lk];
#pragma unroll
    for (int nt = 0; nt < 4; nt++) bfr[nt] = *(const short8*)&Bs[wn + (nt << 4) + lm][lk];
#pragma unroll
    for (int mt = 0; mt < 4; mt++)
#pragma unroll
      for (int nt = 0; nt < 4; nt++)
        acc[mt][nt] = __builtin_amdgcn_mfma_f32_16x16x32_bf16(af[mt], bfr[nt], acc[mt][nt], 0, 0, 0);
    __syncthreads();
  }
#pragma unroll
  for (int nt = 0; nt < 4; nt++){
    int n = bn + wn + (nt << 4) + lm;
    float bia = bias[n];
#pragma unroll
    for (int mt = 0; mt < 4; mt++){
#pragma unroll
      for (int r2 = 0; r2 < 4; r2++){
        int m = bm + wm + (mt << 4) + ((lane >> 4) << 2) + r2;
        float v = acc[mt][nt][r2] + bia;
        if (RELU) v = fmaxf(v, 0.0f);
        if (OUTF32) ((float*)Cv)[(size_t)m * Nd + n] = v;
        else        ((u16*)Cv)[(size_t)m * Nd + n] = f2bf(v);
      }
    }
  }
}

// ---------------- bf16 MFMA GEMM (64x64 tile) for small-M token GEMMs ----------------
template<int RELU, int OUTF32>
__global__ __launch_bounds__(256) void gemm64(const u16* __restrict__ A,
                                              const u16* __restrict__ Bw,
                                              const float* __restrict__ bias,
                                              void* __restrict__ Cv,
                                              int Kd, int Nd){
  __shared__ u16 As[64][40];
  __shared__ u16 Bs[64][40];
  const int t = threadIdx.x;
  const int bm = blockIdx.y << 6;
  const int bn = blockIdx.x << 6;
  const int wave = t >> 6;
  const int lane = t & 63;
  const int wm = (wave & 1) << 5;
  const int wn = (wave >> 1) << 5;
  const int lm = lane & 15;
  const int lk = (lane >> 4) << 3;
  f32x4 acc[2][2] = {};
  for (int k0 = 0; k0 < Kd; k0 += 32){
    {
      int r = t >> 2;
      int c = (t & 3) << 3;
      short8 v = *(const short8*)(A + (size_t)(bm + r) * Kd + k0 + c);
      *(short8*)&As[r][c] = v;
      int kk = t >> 3;
      int nn = (t & 7) << 3;
      short8 w = *(const short8*)(Bw + (size_t)(k0 + kk) * Nd + bn + nn);
#pragma unroll
      for (int q = 0; q < 8; q++) Bs[nn + q][kk] = ((const u16*)&w)[q];
    }
    __syncthreads();
    short8 af[2], bfr[2];
#pragma unroll
    for (int mt = 0; mt < 2; mt++) af[mt] = *(const short8*)&As[wm + (mt << 4) + lm][lk];
#pragma unroll
    for (int nt = 0; nt < 2; nt++) bfr[nt] = *(const short8*)&Bs[wn + (nt << 4) + lm][lk];
#pragma unroll
    for (int mt = 0; mt < 2; mt++)
#pragma unroll
      for (int nt = 0; nt < 2; nt++)
        acc[mt][nt] = __builtin_amdgcn_mfma_f32_16x16x32_bf16(af[mt], bfr[nt], acc[mt][nt], 0, 0, 0);
    __syncthreads();
  }
#pragma unroll
  for (int nt = 0; nt < 2; nt++){
    int n = bn + wn + (nt << 4) + lm;
    float bia = bias[n];
#pragma unroll
    for (int mt = 0; mt < 2; mt++){
#pragma unroll
      for (int r2 = 0; r2 < 4; r2++){
        int m = bm + wm + (mt << 4) + ((lane >> 4) << 2) + r2;
        float v = acc[mt][nt][r2] + bia;
        if (RELU) v = fmaxf(v, 0.0f);
        if (OUTF32) ((float*)Cv)[(size_t)m * Nd + n] = v;
        else        ((u16*)Cv)[(size_t)m * Nd + n] = f2bf(v);
      }
    }
  }
}

// ---------------- GEMM + fused max-pool over 16-row groups (bf16 out) ----------------
__global__ __launch_bounds__(256) void gemm_pool(const u16* __restrict__ A,
                                                 const u16* __restrict__ Bw,
                                                 const float* __restrict__ bias,
                                                 u16* __restrict__ pooled,
                                                 int Kd, int Nd, int groupBase){
  __shared__ u16 As[128][40];
  __shared__ u16 Bs[128][40];
  const int t = threadIdx.x;
  const int bm = blockIdx.y << 7;
  const int bn = blockIdx.x << 7;
  const int wave = t >> 6;
  const int lane = t & 63;
  const int wm = (wave & 1) << 6;
  const int wn = (wave >> 1) << 6;
  const int lm = lane & 15;
  const int lk = (lane >> 4) << 3;
  f32x4 acc[4][4] = {};
  for (int k0 = 0; k0 < Kd; k0 += 32){
#pragma unroll
    for (int it = 0; it < 2; it++){
      int slot = t + (it << 8);
      int r = slot >> 2;
      int c = (slot & 3) << 3;
      short8 v = *(const short8*)(A + (size_t)(bm + r) * Kd + k0 + c);
      *(short8*)&As[r][c] = v;
      int kk = slot >> 4;
      int nn = (slot & 15) << 3;
      short8 w = *(const short8*)(Bw + (size_t)(k0 + kk) * Nd + bn + nn);
#pragma unroll
      for (int q = 0; q < 8; q++) Bs[nn + q][kk] = ((const u16*)&w)[q];
    }
    __syncthreads();
    short8 af[4], bfr[4];
#pragma unroll
    for (int mt = 0; mt < 4; mt++) af[mt] = *(const short8*)&As[wm + (mt << 4) + lm][lk];
#pragma unroll
    for (int nt = 0; nt < 4; nt++) bfr[nt] = *(const short8*)&Bs[wn + (nt << 4) + lm][lk];
#pragma unroll
    for (int mt = 0; mt < 4; mt++)
#pragma unroll
      for (int nt = 0; nt < 4; nt++)
        acc[mt][nt] = __builtin_amdgcn_mfma_f32_16x16x32_bf16(af[mt], bfr[nt], acc[mt][nt], 0, 0, 0);
    __syncthreads();
  }
  // each (mt) tile's 16 rows are exactly one pooling group
#pragma unroll
  for (int nt = 0; nt < 4; nt++){
    int n = bn + wn + (nt << 4) + lm;
    float bia = bias[n];
#pragma unroll
    for (int mt = 0; mt < 4; mt++){
      f32x4 a = acc[mt][nt];
      float v = fmaxf(fmaxf(a[0], a[1]), fmaxf(a[2], a[3]));
      v = fmaxf(v, __shfl_xor(v, 16));
      v = fmaxf(v, __shfl_xor(v, 32));
      if ((lane >> 4) == 0){
        int g = groupBase + (bm >> 4) + (wm >> 4) + mt;
        pooled[(size_t)g * Nd + n] = f2bf(v + bia);
      }
    }
  }
}

// ---------------- tier fallback (f32) ----------------
__global__ __launch_bounds__(256) void fill_diag(float* __restrict__ out, size_t out_elems){
  size_t i = (size_t)blockIdx.x * 256 + threadIdx.x;
  if (i >= out_elems) return;
  size_t maskStart = (size_t)B_ * M_ * D_ + (size_t)B_ * M_ * 4;
  out[i] = (i >= maskStart) ? 1.0f : 0.0f;
}

extern "C" void kernel_launch(void* const* d_in, const int* in_sizes, int n_in,
                              void* d_out, int out_size, void* d_ws, size_t ws_size,
                              hipStream_t stream){
  (void)in_sizes; (void)n_in;
  const float* coords   = (const float*)d_in[0];
  const float* features = (const float*)d_in[1];
  const float* W0 = (const float*)d_in[2];  const float* b0 = (const float*)d_in[3];
  const float* W1 = (const float*)d_in[4];  const float* b1 = (const float*)d_in[5];
  const float* W2 = (const float*)d_in[6];  const float* b2 = (const float*)d_in[7];
  const float* W3 = (const float*)d_in[8];  const float* b3 = (const float*)d_in[9];
  const float* Wn0 = (const float*)d_in[10]; const float* bn0 = (const float*)d_in[11];
  const float* Wn1 = (const float*)d_in[12]; const float* bn1 = (const float*)d_in[13];
  float* out = (float*)d_out;
  const size_t out_elems = (size_t)out_size;

  char* ws = (char*)d_ws;
  const size_t o_cent = 0;            // 16,384
  const size_t o_cntS = 16384;        // 16,384
  const size_t o_knn  = 32768;        // 65,536 -> 98,304
  const size_t o_Wb   = 131072;       // 4,587,520 bf16 W1..Wn1
  const size_t o_pool = 4718592;      // 1,572,864 bf16 [1024,768]
  const size_t o_t1   = 6291456;      // 1,572,864
  const size_t o_chunk= 7864320;      // regA (R*1536 B) + regB (R*1024 B)
  const int ROWS = B_ * M_ * K_;      // 16384

  int R = 16384;
  while (R > 128 && o_chunk + (size_t)R * 2560 > ws_size) R >>= 1;
  if (d_ws == nullptr || o_chunk + (size_t)R * 2560 > ws_size){
    fill_diag<<<(int)((out_elems + 255) / 256), 256, 0, stream>>>(out, out_elems);
    return;
  }

  float* cent_fps    = (float*)(ws + o_cent);
  float* cent_sorted = (float*)(ws + o_cntS);
  int*   knn         = (int*)(ws + o_knn);
  u16* Wb   = (u16*)(ws + o_Wb);
  u16* W1b  = Wb;               u16* W2b  = Wb + 131072;
  u16* W3b  = Wb + 524288;      u16* Wn0b = Wb + 1114112;
  u16* Wn1b = Wb + 1703936;
  u16* pooled = (u16*)(ws + o_pool);
  u16* t1     = (u16*)(ws + o_t1);
  u16* regA   = (u16*)(ws + o_chunk);                      // h1 [R,256] then h3 [R,768]
  u16* regB   = (u16*)(ws + o_chunk + (size_t)R * 1536);   // h2 [R,512]

  conv_wbig<<<8960, 256, 0, stream>>>(W1, W2, W3, Wn0, Wn1, Wb);
  fps_kernel<<<B_, 1024, 0, stream>>>(coords, cent_fps);
  rank_scatter<<<B_, 128, 0, stream>>>(cent_fps, cent_sorted, out, out_elems);
  knn_kernel<<<B_ * M_, KNT, 0, stream>>>(coords, cent_sorted, knn);

  for (int rowBase = 0; rowBase < ROWS; rowBase += R){
    gather_l0<<<R, 256, 0, stream>>>(features, knn, W0, b0, regA, rowBase);
    gemm_bf16<1,0><<<dim3(4, R / 128), 256, 0, stream>>>(regA, W1b, b1, regB, 256, 512);
    gemm_bf16<1,0><<<dim3(6, R / 128), 256, 0, stream>>>(regB, W2b, b2, regA, 512, 768);
    gemm_pool<<<dim3(6, R / 128), 256, 0, stream>>>(regA, W3b, b3, pooled, 768, 768, rowBase >> 4);
  }

  gemm64<1,0><<<dim3(12, (B_ * M_) / 64), 256, 0, stream>>>(pooled, Wn0b, bn0, t1, 768, 768);
  gemm64<0,1><<<dim3(12, (B_ * M_) / 64), 256, 0, stream>>>(t1, Wn1b, bn1, out, 768, 768);
}

// Round 13
// 597.552 us; speedup vs baseline: 2.1080x; 1.3377x over previous
//
#include <hip/hip_runtime.h>

#define B_ 8
#define N_ 16384
#define F_ 6
#define M_ 128
#define K_ 16
#define D_ 768

typedef unsigned short u16;
typedef unsigned int u32;
typedef __attribute__((ext_vector_type(8))) short short8;
typedef __attribute__((ext_vector_type(4))) float f32x4;
typedef __attribute__((ext_vector_type(2))) float f32x2;

__device__ __forceinline__ u16 f2bf(float f){
  union { float f; u32 i; } v; v.f = f;
  u32 x = v.i;
  u32 r = x + 0x7FFFu + ((x >> 16) & 1u);
  return (u16)(r >> 16);
}

// ---------------- weights f32 -> bf16, TRANSPOSED to [n][k] (one-shot) ----------------
__global__ __launch_bounds__(256) void conv_wt(const float* __restrict__ W,
                                               u16* __restrict__ WT, int K, int N){
  __shared__ u16 tile[64][65];
  int tiles_n = N >> 6;
  int tk = blockIdx.x / tiles_n, tn = blockIdx.x % tiles_n;
  int k0 = tk << 6, n0 = tn << 6;
  int t = threadIdx.x;
#pragma unroll
  for (int q = 0; q < 16; q++){
    int idx = q * 256 + t;
    int kk = idx >> 6, nn = idx & 63;
    tile[kk][nn] = f2bf(W[(size_t)(k0 + kk) * N + n0 + nn]);
  }
  __syncthreads();
#pragma unroll
  for (int q = 0; q < 16; q++){
    int idx = q * 256 + t;
    int nn = idx >> 6, kk = idx & 63;
    WT[(size_t)(n0 + nn) * K + k0 + kk] = tile[kk][nn];
  }
}

// ---------------- FPS: packed-f32 distances, paired points, shuffle reduce ----------------
// Thread t owns pairs p = t + j*1024 (j<8) -> points 2p, 2p+1 (adjacent).
// sxy[p] = (x0, x1, y0, y1). z/w/md packed f32x2 in regs. One barrier/step.
__global__ __launch_bounds__(1024) void fps_kernel(const float* __restrict__ coords,
                                                   float* __restrict__ cent){
#pragma clang fp contract(off)
  __shared__ f32x4 sxy[N_ / 2];       // 131072 B
  __shared__ float s_wv[2][16];
  __shared__ int s_wi[2][16];
  int b = blockIdx.x;
  int t = threadIdx.x;
  const float* cb = coords + (size_t)b * N_ * 5;
  f32x2 pz[8], pw[8], md[8];
#pragma unroll
  for (int j = 0; j < 8; j++){
    int p = t + (j << 10);
    size_t i0 = (size_t)(2 * p) * 5, i1 = i0 + 5;
    f32x4 v; v[0] = cb[i0+1]; v[1] = cb[i1+1]; v[2] = cb[i0+2]; v[3] = cb[i1+2];
    sxy[p] = v;
    pz[j] = (f32x2){cb[i0+3], cb[i1+3]};
    pw[j] = (f32x2){cb[i0+4], cb[i1+4]};
    md[j] = (f32x2){1e30f, 1e30f};
  }
  float cx = cb[1], cy = cb[2], cz = cb[3], ct = cb[4];
  if (t == 0){
    float* c0 = cent + (size_t)b * M_ * 4;
    c0[0]=cx; c0[1]=cy; c0[2]=cz; c0[3]=ct;
  }
  __syncthreads();
  for (int step = 1; step < M_; step++){
    f32x2 cx2 = (f32x2){cx, cx}, cy2 = (f32x2){cy, cy};
    f32x2 cz2 = (f32x2){cz, cz}, ct2 = (f32x2){ct, ct};
    float bv = -1.0f; int bi = 1 << 30;
#pragma unroll
    for (int j = 0; j < 8; j++){
      int p = t + (j << 10);
      f32x4 v = sxy[p];                      // ds_read_b128
      f32x2 X = (f32x2){v[0], v[1]};
      f32x2 Y = (f32x2){v[2], v[3]};
      f32x2 dX = X - cx2;                    // v_pk_add_f32
      f32x2 dY = Y - cy2;
      f32x2 s = dX*dX + dY*dY;               // per-point: dx*dx + dy*dy (contract off)
      f32x2 dZ = pz[j] - cz2;
      s = s + dZ*dZ;                         // + dz*dz
      f32x2 dW = pw[j] - ct2;
      s = s + dW*dW;                         // + dw*dw
      f32x2 m = md[j];
      m[0] = (s[0] < m[0]) ? s[0] : m[0];
      m[1] = (s[1] < m[1]) ? s[1] : m[1];
      md[j] = m;
      int i0 = p << 1;
      if (m[0] > bv){ bv = m[0]; bi = i0; }        // ascending-index first-max
      if (m[1] > bv){ bv = m[1]; bi = i0 + 1; }
    }
#pragma unroll
    for (int off = 32; off > 0; off >>= 1){
      float ov = __shfl_down(bv, off);
      int oi = __shfl_down(bi, off);
      if (ov > bv || (ov == bv && oi < bi)){ bv = ov; bi = oi; }
    }
    int par = step & 1;
    if ((t & 63) == 0){ s_wv[par][t >> 6] = bv; s_wi[par][t >> 6] = bi; }
    __syncthreads();                               // only barrier per step
    // 16-slot reduce via shuffle tree (all 16-lane groups converge identically)
    float fv = s_wv[par][t & 15];
    int fi = s_wi[par][t & 15];
#pragma unroll
    for (int off = 1; off < 16; off <<= 1){
      float ov = __shfl_xor(fv, off);
      int oi = __shfl_xor(fi, off);
      if (ov > fv || (ov == fv && oi < fi)){ fv = ov; fi = oi; }
    }
    fi &= (N_ - 1);
    f32x4 vw = sxy[fi >> 1];
    int odd = fi & 1;
    cx = odd ? vw[1] : vw[0];
    cy = odd ? vw[3] : vw[2];
    cz = cb[(size_t)fi*5+3];                       // uniform-address broadcast loads
    ct = cb[(size_t)fi*5+4];
    if (t == 0){
      float* cr = cent + ((size_t)b * M_ + step) * 4;
      cr[0]=cx; cr[1]=cy; cr[2]=cz; cr[3]=ct;
    }
  }
}

// ---------------- stable rank by centroid time; relabel early; f32 outputs ----------------
__global__ __launch_bounds__(128) void rank_scatter(const float* __restrict__ cent_fps,
                                                    float* __restrict__ cent_sorted,
                                                    float* __restrict__ out,
                                                    size_t out_elems){
  int b = blockIdx.x, m = threadIdx.x;
  __shared__ float tt[M_];
  const float* row = cent_fps + ((size_t)b * M_ + m) * 4;
  float x=row[0], y=row[1], z=row[2], w=row[3];
  tt[m] = w;
  __syncthreads();
  int rank = 0;
  for (int j = 0; j < M_; j++){
    float tj = tt[j];
    if (tj < w || (tj == w && j < m)) rank++;       // stable argsort semantics
  }
  float* dst = cent_sorted + ((size_t)b * M_ + rank) * 4;
  dst[0]=x; dst[1]=y; dst[2]=z; dst[3]=w;
  size_t co = (size_t)B_ * M_ * D_ + ((size_t)b * M_ + rank) * 4;
  if (co + 3 < out_elems){
    out[co+0]=x; out[co+1]=y; out[co+2]=z; out[co+3]=w;
  }
  size_t mo = (size_t)B_ * M_ * D_ + (size_t)B_ * M_ * 4 + (size_t)b * M_ + m;
  if (mo < out_elems) out[mo] = 1.0f;              // mask = True -> 1.0f
}

// ---------------- kNN: f32, np op order, stable-min extraction ----------------
#define KNT 512
#define KPT 32
__global__ __launch_bounds__(512) void knn_kernel(const float* __restrict__ coords,
                                                  const float* __restrict__ cent,
                                                  int* __restrict__ knn){
#pragma clang fp contract(off)
  int cm = blockIdx.x;
  int b = cm >> 7;
  const float* cb = coords + (size_t)b * N_ * 5;
  int t = threadIdx.x;
  float cx=cent[cm*4+0], cy=cent[cm*4+1], cz=cent[cm*4+2], ct=cent[cm*4+3];
  float dist[KPT];
#pragma unroll
  for (int j = 0; j < KPT; j++){
    size_t i = t + j * KNT;
    float dx=cb[i*5+1]-cx, dy=cb[i*5+2]-cy, dz=cb[i*5+3]-cz, dw=cb[i*5+4]-ct;
    float d = ((dx*dx + dy*dy) + dz*dz) + dw*dw;
    dist[j] = sqrtf(d);                            // IEEE f32 sqrt = np.sqrt(f32)
  }
  __shared__ float s_wv[8];
  __shared__ int s_wi[8];
  __shared__ int s_bi;
  for (int r = 0; r < K_; r++){
    float bv = 3e38f; int bi = 1 << 30;
#pragma unroll
    for (int j = 0; j < KPT; j++){
      int i = t + j * KNT;
      float v = dist[j];
      if (v < bv){ bv = v; bi = i; }               // first-min kept
    }
#pragma unroll
    for (int off = 32; off > 0; off >>= 1){
      float ov = __shfl_down(bv, off);
      int oi = __shfl_down(bi, off);
      if (ov < bv || (ov == bv && oi < bi)){ bv = ov; bi = oi; }
    }
    if ((t & 63) == 0){ s_wv[t >> 6] = bv; s_wi[t >> 6] = bi; }
    __syncthreads();
    if (t == 0){
      float fv = s_wv[0]; int fi = s_wi[0];
      for (int w = 1; w < 8; w++){
        float wv = s_wv[w]; int wi = s_wi[w];
        if (wv < fv || (wv == fv && wi < fi)){ fv = wv; fi = wi; }
      }
      s_bi = fi;
      knn[(size_t)cm * K_ + r] = fi & (N_ - 1);
    }
    __syncthreads();
    int wi = s_bi;
#pragma unroll
    for (int j = 0; j < KPT; j++){
      if (t + j * KNT == wi) dist[j] = 3e38f;
    }
  }
}

// ---------------- gather + layer0 (6->256, relu), f32 math -> bf16 out ----------------
__global__ __launch_bounds__(256) void gather_l0(const float* __restrict__ feat,
                                                 const int* __restrict__ knn,
                                                 const float* __restrict__ W0,
                                                 const float* __restrict__ b0,
                                                 u16* __restrict__ h1,
                                                 int rowBase){
  int lrow = blockIdx.x;
  int grow = rowBase + lrow;
  int b = grow >> 11;            // /(M*K)=2048
  int t = threadIdx.x;
  __shared__ float sf[F_];
  if (t < F_){
    int idx = knn[grow] & (N_ - 1);
    sf[t] = feat[((size_t)b * N_ + idx) * F_ + t];
  }
  __syncthreads();
  float acc = b0[t];
#pragma unroll
  for (int k = 0; k < F_; k++) acc = fmaf(sf[k], W0[k * 256 + t], acc);
  h1[(size_t)lrow * 256 + t] = f2bf(fmaxf(acc, 0.0f));
}

// ---------------- bf16 MFMA GEMM (128x128 tile), WT[n][k] weights ----------------
template<int RELU, int OUTF32>
__global__ __launch_bounds__(256) void gemm_bf16(const u16* __restrict__ A,
                                                 const u16* __restrict__ WT,
                                                 const float* __restrict__ bias,
                                                 void* __restrict__ Cv,
                                                 int Kd, int Nd){
  __shared__ u16 As[128][40];
  __shared__ u16 Bs[128][40];
  const int t = threadIdx.x;
  const int bm = blockIdx.y << 7;
  const int bn = blockIdx.x << 7;
  const int wave = t >> 6;
  const int lane = t & 63;
  const int wm = (wave & 1) << 6;
  const int wn = (wave >> 1) << 6;
  const int lm = lane & 15;
  const int lk = (lane >> 4) << 3;
  f32x4 acc[4][4] = {};
  for (int k0 = 0; k0 < Kd; k0 += 32){
#pragma unroll
    for (int it = 0; it < 2; it++){
      int slot = t + (it << 8);
      int r = slot >> 2;
      int c = (slot & 3) << 3;
      short8 v = *(const short8*)(A + (size_t)(bm + r) * Kd + k0 + c);
      *(short8*)&As[r][c] = v;
      short8 w = *(const short8*)(WT + (size_t)(bn + r) * Kd + k0 + c);
      *(short8*)&Bs[r][c] = w;
    }
    __syncthreads();
    short8 af[4], bfr[4];
#pragma unroll
    for (int mt = 0; mt < 4; mt++) af[mt] = *(const short8*)&As[wm + (mt << 4) + lm][lk];
#pragma unroll
    for (int nt = 0; nt < 4; nt++) bfr[nt] = *(const short8*)&Bs[wn + (nt << 4) + lm][lk];
#pragma unroll
    for (int mt = 0; mt < 4; mt++)
#pragma unroll
      for (int nt = 0; nt < 4; nt++)
        acc[mt][nt] = __builtin_amdgcn_mfma_f32_16x16x32_bf16(af[mt], bfr[nt], acc[mt][nt], 0, 0, 0);
    __syncthreads();
  }
#pragma unroll
  for (int nt = 0; nt < 4; nt++){
    int n = bn + wn + (nt << 4) + lm;
    float bia = bias[n];
#pragma unroll
    for (int mt = 0; mt < 4; mt++){
#pragma unroll
      for (int r2 = 0; r2 < 4; r2++){
        int m = bm + wm + (mt << 4) + ((lane >> 4) << 2) + r2;
        float v = acc[mt][nt][r2] + bia;
        if (RELU) v = fmaxf(v, 0.0f);
        if (OUTF32) ((float*)Cv)[(size_t)m * Nd + n] = v;
        else        ((u16*)Cv)[(size_t)m * Nd + n] = f2bf(v);
      }
    }
  }
}

// ---------------- bf16 MFMA GEMM (64x64 tile), WT weights, token GEMMs ----------------
template<int RELU, int OUTF32>
__global__ __launch_bounds__(256) void gemm64(const u16* __restrict__ A,
                                              const u16* __restrict__ WT,
                                              const float* __restrict__ bias,
                                              void* __restrict__ Cv,
                                              int Kd, int Nd){
  __shared__ u16 As[64][40];
  __shared__ u16 Bs[64][40];
  const int t = threadIdx.x;
  const int bm = blockIdx.y << 6;
  const int bn = blockIdx.x << 6;
  const int wave = t >> 6;
  const int lane = t & 63;
  const int wm = (wave & 1) << 5;
  const int wn = (wave >> 1) << 5;
  const int lm = lane & 15;
  const int lk = (lane >> 4) << 3;
  f32x4 acc[2][2] = {};
  for (int k0 = 0; k0 < Kd; k0 += 32){
    {
      int r = t >> 2;
      int c = (t & 3) << 3;
      short8 v = *(const short8*)(A + (size_t)(bm + r) * Kd + k0 + c);
      *(short8*)&As[r][c] = v;
      short8 w = *(const short8*)(WT + (size_t)(bn + r) * Kd + k0 + c);
      *(short8*)&Bs[r][c] = w;
    }
    __syncthreads();
    short8 af[2], bfr[2];
#pragma unroll
    for (int mt = 0; mt < 2; mt++) af[mt] = *(const short8*)&As[wm + (mt << 4) + lm][lk];
#pragma unroll
    for (int nt = 0; nt < 2; nt++) bfr[nt] = *(const short8*)&Bs[wn + (nt << 4) + lm][lk];
#pragma unroll
    for (int mt = 0; mt < 2; mt++)
#pragma unroll
      for (int nt = 0; nt < 2; nt++)
        acc[mt][nt] = __builtin_amdgcn_mfma_f32_16x16x32_bf16(af[mt], bfr[nt], acc[mt][nt], 0, 0, 0);
    __syncthreads();
  }
#pragma unroll
  for (int nt = 0; nt < 2; nt++){
    int n = bn + wn + (nt << 4) + lm;
    float bia = bias[n];
#pragma unroll
    for (int mt = 0; mt < 2; mt++){
#pragma unroll
      for (int r2 = 0; r2 < 4; r2++){
        int m = bm + wm + (mt << 4) + ((lane >> 4) << 2) + r2;
        float v = acc[mt][nt][r2] + bia;
        if (RELU) v = fmaxf(v, 0.0f);
        if (OUTF32) ((float*)Cv)[(size_t)m * Nd + n] = v;
        else        ((u16*)Cv)[(size_t)m * Nd + n] = f2bf(v);
      }
    }
  }
}

// ---------------- GEMM + fused max-pool over 16-row groups, WT weights ----------------
__global__ __launch_bounds__(256) void gemm_pool(const u16* __restrict__ A,
                                                 const u16* __restrict__ WT,
                                                 const float* __restrict__ bias,
                                                 u16* __restrict__ pooled,
                                                 int Kd, int Nd, int groupBase){
  __shared__ u16 As[128][40];
  __shared__ u16 Bs[128][40];
  const int t = threadIdx.x;
  const int bm = blockIdx.y << 7;
  const int bn = blockIdx.x << 7;
  const int wave = t >> 6;
  const int lane = t & 63;
  const int wm = (wave & 1) << 6;
  const int wn = (wave >> 1) << 6;
  const int lm = lane & 15;
  const int lk = (lane >> 4) << 3;
  f32x4 acc[4][4] = {};
  for (int k0 = 0; k0 < Kd; k0 += 32){
#pragma unroll
    for (int it = 0; it < 2; it++){
      int slot = t + (it << 8);
      int r = slot >> 2;
      int c = (slot & 3) << 3;
      short8 v = *(const short8*)(A + (size_t)(bm + r) * Kd + k0 + c);
      *(short8*)&As[r][c] = v;
      short8 w = *(const short8*)(WT + (size_t)(bn + r) * Kd + k0 + c);
      *(short8*)&Bs[r][c] = w;
    }
    __syncthreads();
    short8 af[4], bfr[4];
#pragma unroll
    for (int mt = 0; mt < 4; mt++) af[mt] = *(const short8*)&As[wm + (mt << 4) + lm][lk];
#pragma unroll
    for (int nt = 0; nt < 4; nt++) bfr[nt] = *(const short8*)&Bs[wn + (nt << 4) + lm][lk];
#pragma unroll
    for (int mt = 0; mt < 4; mt++)
#pragma unroll
      for (int nt = 0; nt < 4; nt++)
        acc[mt][nt] = __builtin_amdgcn_mfma_f32_16x16x32_bf16(af[mt], bfr[nt], acc[mt][nt], 0, 0, 0);
    __syncthreads();
  }
  // each (mt) tile's 16 rows are exactly one pooling group
#pragma unroll
  for (int nt = 0; nt < 4; nt++){
    int n = bn + wn + (nt << 4) + lm;
    float bia = bias[n];
#pragma unroll
    for (int mt = 0; mt < 4; mt++){
      f32x4 a = acc[mt][nt];
      float v = fmaxf(fmaxf(a[0], a[1]), fmaxf(a[2], a[3]));
      v = fmaxf(v, __shfl_xor(v, 16));
      v = fmaxf(v, __shfl_xor(v, 32));
      if ((lane >> 4) == 0){
        int g = groupBase + (bm >> 4) + (wm >> 4) + mt;
        pooled[(size_t)g * Nd + n] = f2bf(v + bia);
      }
    }
  }
}

// ---------------- tier fallback (f32) ----------------
__global__ __launch_bounds__(256) void fill_diag(float* __restrict__ out, size_t out_elems){
  size_t i = (size_t)blockIdx.x * 256 + threadIdx.x;
  if (i >= out_elems) return;
  size_t maskStart = (size_t)B_ * M_ * D_ + (size_t)B_ * M_ * 4;
  out[i] = (i >= maskStart) ? 1.0f : 0.0f;
}

extern "C" void kernel_launch(void* const* d_in, const int* in_sizes, int n_in,
                              void* d_out, int out_size, void* d_ws, size_t ws_size,
                              hipStream_t stream){
  (void)in_sizes; (void)n_in;
  const float* coords   = (const float*)d_in[0];
  const float* features = (const float*)d_in[1];
  const float* W0 = (const float*)d_in[2];  const float* b0 = (const float*)d_in[3];
  const float* W1 = (const float*)d_in[4];  const float* b1 = (const float*)d_in[5];
  const float* W2 = (const float*)d_in[6];  const float* b2 = (const float*)d_in[7];
  const float* W3 = (const float*)d_in[8];  const float* b3 = (const float*)d_in[9];
  const float* Wn0 = (const float*)d_in[10]; const float* bn0 = (const float*)d_in[11];
  const float* Wn1 = (const float*)d_in[12]; const float* bn1 = (const float*)d_in[13];
  float* out = (float*)d_out;
  const size_t out_elems = (size_t)out_size;

  char* ws = (char*)d_ws;
  const size_t o_cent = 0;            // 16,384
  const size_t o_cntS = 16384;        // 16,384
  const size_t o_knn  = 32768;        // 65,536 -> 98,304
  const size_t o_Wb   = 131072;       // 4,587,520 bf16 W1t..Wn1t (transposed)
  const size_t o_pool = 4718592;      // 1,572,864 bf16 [1024,768]
  const size_t o_t1   = 6291456;      // 1,572,864
  const size_t o_chunk= 7864320;      // regA (R*1536 B) + regB (R*1024 B)
  const int ROWS = B_ * M_ * K_;      // 16384

  int R = 16384;
  while (R > 128 && o_chunk + (size_t)R * 2560 > ws_size) R >>= 1;
  if (d_ws == nullptr || o_chunk + (size_t)R * 2560 > ws_size){
    fill_diag<<<(int)((out_elems + 255) / 256), 256, 0, stream>>>(out, out_elems);
    return;
  }

  float* cent_fps    = (float*)(ws + o_cent);
  float* cent_sorted = (float*)(ws + o_cntS);
  int*   knn         = (int*)(ws + o_knn);
  u16* Wb   = (u16*)(ws + o_Wb);
  u16* W1t  = Wb;               u16* W2t  = Wb + 131072;
  u16* W3t  = Wb + 524288;      u16* Wn0t = Wb + 1114112;
  u16* Wn1t = Wb + 1703936;
  u16* pooled = (u16*)(ws + o_pool);
  u16* t1     = (u16*)(ws + o_t1);
  u16* regA   = (u16*)(ws + o_chunk);                      // h1 [R,256] then h3 [R,768]
  u16* regB   = (u16*)(ws + o_chunk + (size_t)R * 1536);   // h2 [R,512]

  conv_wt<<< 32, 256, 0, stream>>>(W1,  W1t,  256, 512);
  conv_wt<<< 96, 256, 0, stream>>>(W2,  W2t,  512, 768);
  conv_wt<<<144, 256, 0, stream>>>(W3,  W3t,  768, 768);
  conv_wt<<<144, 256, 0, stream>>>(Wn0, Wn0t, 768, 768);
  conv_wt<<<144, 256, 0, stream>>>(Wn1, Wn1t, 768, 768);

  fps_kernel<<<B_, 1024, 0, stream>>>(coords, cent_fps);
  rank_scatter<<<B_, 128, 0, stream>>>(cent_fps, cent_sorted, out, out_elems);
  knn_kernel<<<B_ * M_, KNT, 0, stream>>>(coords, cent_sorted, knn);

  for (int rowBase = 0; rowBase < ROWS; rowBase += R){
    gather_l0<<<R, 256, 0, stream>>>(features, knn, W0, b0, regA, rowBase);
    gemm_bf16<1,0><<<dim3(4, R / 128), 256, 0, stream>>>(regA, W1t, b1, regB, 256, 512);
    gemm_bf16<1,0><<<dim3(6, R / 128), 256, 0, stream>>>(regB, W2t, b2, regA, 512, 768);
    gemm_pool<<<dim3(6, R / 128), 256, 0, stream>>>(regA, W3t, b3, pooled, 768, 768, rowBase >> 4);
  }

  gemm64<1,0><<<dim3(12, (B_ * M_) / 64), 256, 0, stream>>>(pooled, Wn0t, bn0, t1, 768, 768);
  gemm64<0,1><<<dim3(12, (B_ * M_) / 64), 256, 0, stream>>>(t1, Wn1t, bn1, out, 768, 768);
}

// Round 14
// 571.290 us; speedup vs baseline: 2.2049x; 1.0460x over previous
//
#include <hip/hip_runtime.h>

#define B_ 8
#define N_ 16384
#define F_ 6
#define M_ 128
#define K_ 16
#define D_ 768

typedef unsigned short u16;
typedef unsigned int u32;
typedef __attribute__((ext_vector_type(8))) short short8;
typedef __attribute__((ext_vector_type(4))) float f32x4;
typedef __attribute__((ext_vector_type(2))) float f32x2;

__device__ __forceinline__ u16 f2bf(float f){
  union { float f; u32 i; } v; v.f = f;
  u32 x = v.i;
  u32 r = x + 0x7FFFu + ((x >> 16) & 1u);
  return (u16)(r >> 16);
}

// ---------------- weights f32 -> bf16, TRANSPOSED to [n][k] (one-shot) ----------------
__global__ __launch_bounds__(256) void conv_wt(const float* __restrict__ W,
                                               u16* __restrict__ WT, int K, int N){
  __shared__ u16 tile[64][65];
  int tiles_n = N >> 6;
  int tk = blockIdx.x / tiles_n, tn = blockIdx.x % tiles_n;
  int k0 = tk << 6, n0 = tn << 6;
  int t = threadIdx.x;
#pragma unroll
  for (int q = 0; q < 16; q++){
    int idx = q * 256 + t;
    int kk = idx >> 6, nn = idx & 63;
    tile[kk][nn] = f2bf(W[(size_t)(k0 + kk) * N + n0 + nn]);
  }
  __syncthreads();
#pragma unroll
  for (int q = 0; q < 16; q++){
    int idx = q * 256 + t;
    int nn = idx >> 6, kk = idx & 63;
    WT[(size_t)(n0 + nn) * K + k0 + kk] = tile[kk][nn];
  }
}

// ---------------- FPS: all-register point set, 512 threads, no hot-loop LDS ----------------
// Thread t owns pairs p = t + j*512 (j<16) -> points 2p, 2p+1 (ascending order).
// __launch_bounds__(512,2): 2 waves/SIMD -> VGPR cap 256; live set ~180 regs.
#define FPW 16
__global__ __launch_bounds__(512, 2) void fps_kernel(const float* __restrict__ coords,
                                                     float* __restrict__ cent){
#pragma clang fp contract(off)
  __shared__ float s_wv[2][8];
  __shared__ int s_wi[2][8];
  int b = blockIdx.x;
  int t = threadIdx.x;
  const float* cb = coords + (size_t)b * N_ * 5;
  f32x2 px[FPW], py[FPW], pz[FPW], pw[FPW], md[FPW];
#pragma unroll
  for (int j = 0; j < FPW; j++){
    int p = t + (j << 9);
    size_t i0 = (size_t)(2 * p) * 5;
    px[j] = (f32x2){cb[i0+1], cb[i0+6]};
    py[j] = (f32x2){cb[i0+2], cb[i0+7]};
    pz[j] = (f32x2){cb[i0+3], cb[i0+8]};
    pw[j] = (f32x2){cb[i0+4], cb[i0+9]};
    md[j] = (f32x2){1e30f, 1e30f};
  }
  float cx = cb[1], cy = cb[2], cz = cb[3], ct = cb[4];
  if (t == 0){
    float* c0 = cent + (size_t)b * M_ * 4;
    c0[0]=cx; c0[1]=cy; c0[2]=cz; c0[3]=ct;
  }
  for (int step = 1; step < M_; step++){
    f32x2 cx2 = (f32x2){cx, cx}, cy2 = (f32x2){cy, cy};
    f32x2 cz2 = (f32x2){cz, cz}, ct2 = (f32x2){ct, ct};
    float bv = -1.0f; int bi = 1 << 30;
#pragma unroll
    for (int j = 0; j < FPW; j++){
      f32x2 dX = px[j] - cx2;
      f32x2 dY = py[j] - cy2;
      f32x2 s = dX*dX + dY*dY;               // per-point numpy order (contract off)
      f32x2 dZ = pz[j] - cz2;
      s = s + dZ*dZ;
      f32x2 dW = pw[j] - ct2;
      s = s + dW*dW;
      f32x2 m = md[j];
      m[0] = (s[0] < m[0]) ? s[0] : m[0];
      m[1] = (s[1] < m[1]) ? s[1] : m[1];
      md[j] = m;
      int i0 = (t + (j << 9)) << 1;
      if (m[0] > bv){ bv = m[0]; bi = i0; }        // ascending-index first-max
      if (m[1] > bv){ bv = m[1]; bi = i0 + 1; }
    }
#pragma unroll
    for (int off = 32; off > 0; off >>= 1){
      float ov = __shfl_down(bv, off);
      int oi = __shfl_down(bi, off);
      if (ov > bv || (ov == bv && oi < bi)){ bv = ov; bi = oi; }
    }
    int par = step & 1;
    if ((t & 63) == 0){ s_wv[par][t >> 6] = bv; s_wi[par][t >> 6] = bi; }
    __syncthreads();                               // only barrier per step
    float fv = s_wv[par][t & 7];
    int fi = s_wi[par][t & 7];
#pragma unroll
    for (int off = 1; off < 8; off <<= 1){
      float ov = __shfl_xor(fv, off);
      int oi = __shfl_xor(fi, off);
      if (ov > fv || (ov == fv && oi < fi)){ fv = ov; fi = oi; }
    }
    fi &= (N_ - 1);
    // winner coords via uniform-address global loads (L1 broadcast; no 2nd barrier)
    size_t wbase = (size_t)fi * 5;
    cx = cb[wbase+1]; cy = cb[wbase+2]; cz = cb[wbase+3]; ct = cb[wbase+4];
    if (t == 0){
      float* cr = cent + ((size_t)b * M_ + step) * 4;
      cr[0]=cx; cr[1]=cy; cr[2]=cz; cr[3]=ct;
    }
  }
}

// ---------------- stable rank by centroid time; relabel early; f32 outputs ----------------
__global__ __launch_bounds__(128) void rank_scatter(const float* __restrict__ cent_fps,
                                                    float* __restrict__ cent_sorted,
                                                    float* __restrict__ out,
                                                    size_t out_elems){
  int b = blockIdx.x, m = threadIdx.x;
  __shared__ float tt[M_];
  const float* row = cent_fps + ((size_t)b * M_ + m) * 4;
  float x=row[0], y=row[1], z=row[2], w=row[3];
  tt[m] = w;
  __syncthreads();
  int rank = 0;
  for (int j = 0; j < M_; j++){
    float tj = tt[j];
    if (tj < w || (tj == w && j < m)) rank++;       // stable argsort semantics
  }
  float* dst = cent_sorted + ((size_t)b * M_ + rank) * 4;
  dst[0]=x; dst[1]=y; dst[2]=z; dst[3]=w;
  size_t co = (size_t)B_ * M_ * D_ + ((size_t)b * M_ + rank) * 4;
  if (co + 3 < out_elems){
    out[co+0]=x; out[co+1]=y; out[co+2]=z; out[co+3]=w;
  }
  size_t mo = (size_t)B_ * M_ * D_ + (size_t)B_ * M_ * 4 + (size_t)b * M_ + m;
  if (mo < out_elems) out[mo] = 1.0f;              // mask = True -> 1.0f
}

// ---------------- kNN: f32, np op order, stable-min extraction ----------------
#define KNT 512
#define KPT 32
__global__ __launch_bounds__(512) void knn_kernel(const float* __restrict__ coords,
                                                  const float* __restrict__ cent,
                                                  int* __restrict__ knn){
#pragma clang fp contract(off)
  int cm = blockIdx.x;
  int b = cm >> 7;
  const float* cb = coords + (size_t)b * N_ * 5;
  int t = threadIdx.x;
  float cx=cent[cm*4+0], cy=cent[cm*4+1], cz=cent[cm*4+2], ct=cent[cm*4+3];
  float dist[KPT];
#pragma unroll
  for (int j = 0; j < KPT; j++){
    size_t i = t + j * KNT;
    float dx=cb[i*5+1]-cx, dy=cb[i*5+2]-cy, dz=cb[i*5+3]-cz, dw=cb[i*5+4]-ct;
    float d = ((dx*dx + dy*dy) + dz*dz) + dw*dw;
    dist[j] = sqrtf(d);                            // IEEE f32 sqrt = np.sqrt(f32)
  }
  __shared__ float s_wv[8];
  __shared__ int s_wi[8];
  __shared__ int s_bi;
  for (int r = 0; r < K_; r++){
    float bv = 3e38f; int bi = 1 << 30;
#pragma unroll
    for (int j = 0; j < KPT; j++){
      int i = t + j * KNT;
      float v = dist[j];
      if (v < bv){ bv = v; bi = i; }               // first-min kept
    }
#pragma unroll
    for (int off = 32; off > 0; off >>= 1){
      float ov = __shfl_down(bv, off);
      int oi = __shfl_down(bi, off);
      if (ov < bv || (ov == bv && oi < bi)){ bv = ov; bi = oi; }
    }
    if ((t & 63) == 0){ s_wv[t >> 6] = bv; s_wi[t >> 6] = bi; }
    __syncthreads();
    if (t == 0){
      float fv = s_wv[0]; int fi = s_wi[0];
      for (int w = 1; w < 8; w++){
        float wv = s_wv[w]; int wi = s_wi[w];
        if (wv < fv || (wv == fv && wi < fi)){ fv = wv; fi = wi; }
      }
      s_bi = fi;
      knn[(size_t)cm * K_ + r] = fi & (N_ - 1);
    }
    __syncthreads();
    int wi = s_bi;
#pragma unroll
    for (int j = 0; j < KPT; j++){
      if (t + j * KNT == wi) dist[j] = 3e38f;
    }
  }
}

// ---------------- gather + layer0: 32 rows/block, W0/b0/features LDS-staged ----------------
__global__ __launch_bounds__(256) void gather_l0(const float* __restrict__ feat,
                                                 const int* __restrict__ knn,
                                                 const float* __restrict__ W0,
                                                 const float* __restrict__ b0,
                                                 u16* __restrict__ h1,
                                                 int rowBase){
  __shared__ float sW[F_][256];
  __shared__ float sb[256];
  __shared__ float sfa[32][F_];
  int t = threadIdx.x;
#pragma unroll
  for (int k = 0; k < F_; k++) sW[k][t] = W0[k * 256 + t];
  sb[t] = b0[t];
  if (t < 32 * F_){
    int r = t / F_, k = t % F_;
    int grow = rowBase + blockIdx.x * 32 + r;
    int bb = grow >> 11;                          // /(M*K)=2048
    int idx = knn[grow] & (N_ - 1);
    sfa[r][k] = feat[((size_t)bb * N_ + idx) * F_ + k];
  }
  __syncthreads();
#pragma unroll 4
  for (int r = 0; r < 32; r++){
    float acc = sb[t];
#pragma unroll
    for (int k = 0; k < F_; k++) acc = fmaf(sfa[r][k], sW[k][t], acc);
    int lrow = blockIdx.x * 32 + r;
    h1[(size_t)lrow * 256 + t] = f2bf(fmaxf(acc, 0.0f));
  }
}

// ---------------- bf16 MFMA GEMM (128x128 tile), WT[n][k] weights ----------------
template<int RELU, int OUTF32>
__global__ __launch_bounds__(256) void gemm_bf16(const u16* __restrict__ A,
                                                 const u16* __restrict__ WT,
                                                 const float* __restrict__ bias,
                                                 void* __restrict__ Cv,
                                                 int Kd, int Nd){
  __shared__ u16 As[128][40];
  __shared__ u16 Bs[128][40];
  const int t = threadIdx.x;
  const int bm = blockIdx.y << 7;
  const int bn = blockIdx.x << 7;
  const int wave = t >> 6;
  const int lane = t & 63;
  const int wm = (wave & 1) << 6;
  const int wn = (wave >> 1) << 6;
  const int lm = lane & 15;
  const int lk = (lane >> 4) << 3;
  f32x4 acc[4][4] = {};
  for (int k0 = 0; k0 < Kd; k0 += 32){
#pragma unroll
    for (int it = 0; it < 2; it++){
      int slot = t + (it << 8);
      int r = slot >> 2;
      int c = (slot & 3) << 3;
      short8 v = *(const short8*)(A + (size_t)(bm + r) * Kd + k0 + c);
      *(short8*)&As[r][c] = v;
      short8 w = *(const short8*)(WT + (size_t)(bn + r) * Kd + k0 + c);
      *(short8*)&Bs[r][c] = w;
    }
    __syncthreads();
    short8 af[4], bfr[4];
#pragma unroll
    for (int mt = 0; mt < 4; mt++) af[mt] = *(const short8*)&As[wm + (mt << 4) + lm][lk];
#pragma unroll
    for (int nt = 0; nt < 4; nt++) bfr[nt] = *(const short8*)&Bs[wn + (nt << 4) + lm][lk];
#pragma unroll
    for (int mt = 0; mt < 4; mt++)
#pragma unroll
      for (int nt = 0; nt < 4; nt++)
        acc[mt][nt] = __builtin_amdgcn_mfma_f32_16x16x32_bf16(af[mt], bfr[nt], acc[mt][nt], 0, 0, 0);
    __syncthreads();
  }
#pragma unroll
  for (int nt = 0; nt < 4; nt++){
    int n = bn + wn + (nt << 4) + lm;
    float bia = bias[n];
#pragma unroll
    for (int mt = 0; mt < 4; mt++){
#pragma unroll
      for (int r2 = 0; r2 < 4; r2++){
        int m = bm + wm + (mt << 4) + ((lane >> 4) << 2) + r2;
        float v = acc[mt][nt][r2] + bia;
        if (RELU) v = fmaxf(v, 0.0f);
        if (OUTF32) ((float*)Cv)[(size_t)m * Nd + n] = v;
        else        ((u16*)Cv)[(size_t)m * Nd + n] = f2bf(v);
      }
    }
  }
}

// ---------------- bf16 MFMA GEMM (64x64 tile), WT weights, token GEMMs ----------------
template<int RELU, int OUTF32>
__global__ __launch_bounds__(256) void gemm64(const u16* __restrict__ A,
                                              const u16* __restrict__ WT,
                                              const float* __restrict__ bias,
                                              void* __restrict__ Cv,
                                              int Kd, int Nd){
  __shared__ u16 As[64][40];
  __shared__ u16 Bs[64][40];
  const int t = threadIdx.x;
  const int bm = blockIdx.y << 6;
  const int bn = blockIdx.x << 6;
  const int wave = t >> 6;
  const int lane = t & 63;
  const int wm = (wave & 1) << 5;
  const int wn = (wave >> 1) << 5;
  const int lm = lane & 15;
  const int lk = (lane >> 4) << 3;
  f32x4 acc[2][2] = {};
  for (int k0 = 0; k0 < Kd; k0 += 32){
    {
      int r = t >> 2;
      int c = (t & 3) << 3;
      short8 v = *(const short8*)(A + (size_t)(bm + r) * Kd + k0 + c);
      *(short8*)&As[r][c] = v;
      short8 w = *(const short8*)(WT + (size_t)(bn + r) * Kd + k0 + c);
      *(short8*)&Bs[r][c] = w;
    }
    __syncthreads();
    short8 af[2], bfr[2];
#pragma unroll
    for (int mt = 0; mt < 2; mt++) af[mt] = *(const short8*)&As[wm + (mt << 4) + lm][lk];
#pragma unroll
    for (int nt = 0; nt < 2; nt++) bfr[nt] = *(const short8*)&Bs[wn + (nt << 4) + lm][lk];
#pragma unroll
    for (int mt = 0; mt < 2; mt++)
#pragma unroll
      for (int nt = 0; nt < 2; nt++)
        acc[mt][nt] = __builtin_amdgcn_mfma_f32_16x16x32_bf16(af[mt], bfr[nt], acc[mt][nt], 0, 0, 0);
    __syncthreads();
  }
#pragma unroll
  for (int nt = 0; nt < 2; nt++){
    int n = bn + wn + (nt << 4) + lm;
    float bia = bias[n];
#pragma unroll
    for (int mt = 0; mt < 2; mt++){
#pragma unroll
      for (int r2 = 0; r2 < 4; r2++){
        int m = bm + wm + (mt << 4) + ((lane >> 4) << 2) + r2;
        float v = acc[mt][nt][r2] + bia;
        if (RELU) v = fmaxf(v, 0.0f);
        if (OUTF32) ((float*)Cv)[(size_t)m * Nd + n] = v;
        else        ((u16*)Cv)[(size_t)m * Nd + n] = f2bf(v);
      }
    }
  }
}

// ---------------- GEMM + fused max-pool over 16-row groups, WT weights ----------------
__global__ __launch_bounds__(256) void gemm_pool(const u16* __restrict__ A,
                                                 const u16* __restrict__ WT,
                                                 const float* __restrict__ bias,
                                                 u16* __restrict__ pooled,
                                                 int Kd, int Nd, int groupBase){
  __shared__ u16 As[128][40];
  __shared__ u16 Bs[128][40];
  const int t = threadIdx.x;
  const int bm = blockIdx.y << 7;
  const int bn = blockIdx.x << 7;
  const int wave = t >> 6;
  const int lane = t & 63;
  const int wm = (wave & 1) << 6;
  const int wn = (wave >> 1) << 6;
  const int lm = lane & 15;
  const int lk = (lane >> 4) << 3;
  f32x4 acc[4][4] = {};
  for (int k0 = 0; k0 < Kd; k0 += 32){
#pragma unroll
    for (int it = 0; it < 2; it++){
      int slot = t + (it << 8);
      int r = slot >> 2;
      int c = (slot & 3) << 3;
      short8 v = *(const short8*)(A + (size_t)(bm + r) * Kd + k0 + c);
      *(short8*)&As[r][c] = v;
      short8 w = *(const short8*)(WT + (size_t)(bn + r) * Kd + k0 + c);
      *(short8*)&Bs[r][c] = w;
    }
    __syncthreads();
    short8 af[4], bfr[4];
#pragma unroll
    for (int mt = 0; mt < 4; mt++) af[mt] = *(const short8*)&As[wm + (mt << 4) + lm][lk];
#pragma unroll
    for (int nt = 0; nt < 4; nt++) bfr[nt] = *(const short8*)&Bs[wn + (nt << 4) + lm][lk];
#pragma unroll
    for (int mt = 0; mt < 4; mt++)
#pragma unroll
      for (int nt = 0; nt < 4; nt++)
        acc[mt][nt] = __builtin_amdgcn_mfma_f32_16x16x32_bf16(af[mt], bfr[nt], acc[mt][nt], 0, 0, 0);
    __syncthreads();
  }
  // each (mt) tile's 16 rows are exactly one pooling group
#pragma unroll
  for (int nt = 0; nt < 4; nt++){
    int n = bn + wn + (nt << 4) + lm;
    float bia = bias[n];
#pragma unroll
    for (int mt = 0; mt < 4; mt++){
      f32x4 a = acc[mt][nt];
      float v = fmaxf(fmaxf(a[0], a[1]), fmaxf(a[2], a[3]));
      v = fmaxf(v, __shfl_xor(v, 16));
      v = fmaxf(v, __shfl_xor(v, 32));
      if ((lane >> 4) == 0){
        int g = groupBase + (bm >> 4) + (wm >> 4) + mt;
        pooled[(size_t)g * Nd + n] = f2bf(v + bia);
      }
    }
  }
}

// ---------------- tier fallback (f32) ----------------
__global__ __launch_bounds__(256) void fill_diag(float* __restrict__ out, size_t out_elems){
  size_t i = (size_t)blockIdx.x * 256 + threadIdx.x;
  if (i >= out_elems) return;
  size_t maskStart = (size_t)B_ * M_ * D_ + (size_t)B_ * M_ * 4;
  out[i] = (i >= maskStart) ? 1.0f : 0.0f;
}

extern "C" void kernel_launch(void* const* d_in, const int* in_sizes, int n_in,
                              void* d_out, int out_size, void* d_ws, size_t ws_size,
                              hipStream_t stream){
  (void)in_sizes; (void)n_in;
  const float* coords   = (const float*)d_in[0];
  const float* features = (const float*)d_in[1];
  const float* W0 = (const float*)d_in[2];  const float* b0 = (const float*)d_in[3];
  const float* W1 = (const float*)d_in[4];  const float* b1 = (const float*)d_in[5];
  const float* W2 = (const float*)d_in[6];  const float* b2 = (const float*)d_in[7];
  const float* W3 = (const float*)d_in[8];  const float* b3 = (const float*)d_in[9];
  const float* Wn0 = (const float*)d_in[10]; const float* bn0 = (const float*)d_in[11];
  const float* Wn1 = (const float*)d_in[12]; const float* bn1 = (const float*)d_in[13];
  float* out = (float*)d_out;
  const size_t out_elems = (size_t)out_size;

  char* ws = (char*)d_ws;
  const size_t o_cent = 0;            // 16,384
  const size_t o_cntS = 16384;        // 16,384
  const size_t o_knn  = 32768;        // 65,536 -> 98,304
  const size_t o_Wb   = 131072;       // 4,587,520 bf16 W1t..Wn1t (transposed)
  const size_t o_pool = 4718592;      // 1,572,864 bf16 [1024,768]
  const size_t o_t1   = 6291456;      // 1,572,864
  const size_t o_chunk= 7864320;      // regA (R*1536 B) + regB (R*1024 B)
  const int ROWS = B_ * M_ * K_;      // 16384

  int R = 16384;
  while (R > 128 && o_chunk + (size_t)R * 2560 > ws_size) R >>= 1;
  if (d_ws == nullptr || o_chunk + (size_t)R * 2560 > ws_size){
    fill_diag<<<(int)((out_elems + 255) / 256), 256, 0, stream>>>(out, out_elems);
    return;
  }

  float* cent_fps    = (float*)(ws + o_cent);
  float* cent_sorted = (float*)(ws + o_cntS);
  int*   knn         = (int*)(ws + o_knn);
  u16* Wb   = (u16*)(ws + o_Wb);
  u16* W1t  = Wb;               u16* W2t  = Wb + 131072;
  u16* W3t  = Wb + 524288;      u16* Wn0t = Wb + 1114112;
  u16* Wn1t = Wb + 1703936;
  u16* pooled = (u16*)(ws + o_pool);
  u16* t1     = (u16*)(ws + o_t1);
  u16* regA   = (u16*)(ws + o_chunk);                      // h1 [R,256] then h3 [R,768]
  u16* regB   = (u16*)(ws + o_chunk + (size_t)R * 1536);   // h2 [R,512]

  conv_wt<<< 32, 256, 0, stream>>>(W1,  W1t,  256, 512);
  conv_wt<<< 96, 256, 0, stream>>>(W2,  W2t,  512, 768);
  conv_wt<<<144, 256, 0, stream>>>(W3,  W3t,  768, 768);
  conv_wt<<<144, 256, 0, stream>>>(Wn0, Wn0t, 768, 768);
  conv_wt<<<144, 256, 0, stream>>>(Wn1, Wn1t, 768, 768);

  fps_kernel<<<B_, 512, 0, stream>>>(coords, cent_fps);
  rank_scatter<<<B_, 128, 0, stream>>>(cent_fps, cent_sorted, out, out_elems);
  knn_kernel<<<B_ * M_, KNT, 0, stream>>>(coords, cent_sorted, knn);

  for (int rowBase = 0; rowBase < ROWS; rowBase += R){
    gather_l0<<<R / 32, 256, 0, stream>>>(features, knn, W0, b0, regA, rowBase);
    gemm_bf16<1,0><<<dim3(4, R / 128), 256, 0, stream>>>(regA, W1t, b1, regB, 256, 512);
    gemm_bf16<1,0><<<dim3(6, R / 128), 256, 0, stream>>>(regB, W2t, b2, regA, 512, 768);
    gemm_pool<<<dim3(6, R / 128), 256, 0, stream>>>(regA, W3t, b3, pooled, 768, 768, rowBase >> 4);
  }

  gemm64<1,0><<<dim3(12, (B_ * M_) / 64), 256, 0, stream>>>(pooled, Wn0t, bn0, t1, 768, 768);
  gemm64<0,1><<<dim3(12, (B_ * M_) / 64), 256, 0, stream>>>(t1, Wn1t, bn1, out, 768, 768);
}

// Round 15
// 566.931 us; speedup vs baseline: 2.2218x; 1.0077x over previous
//
#include <hip/hip_runtime.h>

#define B_ 8
#define N_ 16384
#define F_ 6
#define M_ 128
#define K_ 16
#define D_ 768

typedef unsigned short u16;
typedef unsigned int u32;
typedef __attribute__((ext_vector_type(8))) short short8;
typedef __attribute__((ext_vector_type(4))) float f32x4;
typedef __attribute__((ext_vector_type(2))) float f32x2;

__device__ __forceinline__ u16 f2bf(float f){
  union { float f; u32 i; } v; v.f = f;
  u32 x = v.i;
  u32 r = x + 0x7FFFu + ((x >> 16) & 1u);
  return (u16)(r >> 16);
}

// ---------------- all weights f32 -> bf16 transposed [n][k], ONE kernel ----------------
__global__ __launch_bounds__(256) void conv_all(const float* __restrict__ W1,
                                                const float* __restrict__ W2,
                                                const float* __restrict__ W3,
                                                const float* __restrict__ Wn0,
                                                const float* __restrict__ Wn1,
                                                u16* __restrict__ Wb){
  __shared__ u16 tile[64][65];
  int blk = blockIdx.x;
  const float* W; u16* WT; int K, N, lb;
  if      (blk < 32)  { W = W1;  WT = Wb;           K = 256; N = 512; lb = blk; }
  else if (blk < 128) { W = W2;  WT = Wb + 131072;  K = 512; N = 768; lb = blk - 32; }
  else if (blk < 272) { W = W3;  WT = Wb + 524288;  K = 768; N = 768; lb = blk - 128; }
  else if (blk < 416) { W = Wn0; WT = Wb + 1114112; K = 768; N = 768; lb = blk - 272; }
  else                { W = Wn1; WT = Wb + 1703936; K = 768; N = 768; lb = blk - 416; }
  int tiles_n = N >> 6;
  int tk = lb / tiles_n, tn = lb % tiles_n;
  int k0 = tk << 6, n0 = tn << 6;
  int t = threadIdx.x;
#pragma unroll
  for (int q = 0; q < 16; q++){
    int idx = q * 256 + t;
    int kk = idx >> 6, nn = idx & 63;
    tile[kk][nn] = f2bf(W[(size_t)(k0 + kk) * N + n0 + nn]);
  }
  __syncthreads();
#pragma unroll
  for (int q = 0; q < 16; q++){
    int idx = q * 256 + t;
    int nn = idx >> 6, kk = idx & 63;
    WT[(size_t)(n0 + nn) * K + k0 + kk] = tile[kk][nn];
  }
}

// ---------------- FPS + fused time-sort scatter ----------------
// 512 thr, pairs in registers, scalar (uniform) winner fetch, cent mirrored in LDS;
// tail does the stable rank + writes cent_sorted + out cent/mask sections.
#define FPW 16
__global__ __launch_bounds__(512, 2) void fps_kernel(const float* __restrict__ coords,
                                                     float* __restrict__ cent_sorted,
                                                     float* __restrict__ out,
                                                     size_t out_elems){
#pragma clang fp contract(off)
  __shared__ float s_wv[2][8];
  __shared__ int s_wi[2][8];
  __shared__ f32x4 s_cent[M_];
  int b = blockIdx.x;
  int t = threadIdx.x;
  const float* cb = coords + (size_t)b * N_ * 5;
  f32x2 px[FPW], py[FPW], pz[FPW], pw[FPW], md[FPW];
#pragma unroll
  for (int j = 0; j < FPW; j++){
    int p = t + (j << 9);
    size_t i0 = (size_t)(2 * p) * 5;
    px[j] = (f32x2){cb[i0+1], cb[i0+6]};
    py[j] = (f32x2){cb[i0+2], cb[i0+7]};
    pz[j] = (f32x2){cb[i0+3], cb[i0+8]};
    pw[j] = (f32x2){cb[i0+4], cb[i0+9]};
    md[j] = (f32x2){1e30f, 1e30f};
  }
  float cx = cb[1], cy = cb[2], cz = cb[3], ct = cb[4];
  if (t == 0) s_cent[0] = (f32x4){cx, cy, cz, ct};
  for (int step = 1; step < M_; step++){
    f32x2 cx2 = (f32x2){cx, cx}, cy2 = (f32x2){cy, cy};
    f32x2 cz2 = (f32x2){cz, cz}, ct2 = (f32x2){ct, ct};
    float bv = -1.0f; int bi = 1 << 30;
#pragma unroll
    for (int j = 0; j < FPW; j++){
      f32x2 dX = px[j] - cx2;
      f32x2 dY = py[j] - cy2;
      f32x2 s = dX*dX + dY*dY;               // per-point numpy order (contract off)
      f32x2 dZ = pz[j] - cz2;
      s = s + dZ*dZ;
      f32x2 dW = pw[j] - ct2;
      s = s + dW*dW;
      f32x2 m = md[j];
      m[0] = (s[0] < m[0]) ? s[0] : m[0];
      m[1] = (s[1] < m[1]) ? s[1] : m[1];
      md[j] = m;
      int i0 = (t + (j << 9)) << 1;
      if (m[0] > bv){ bv = m[0]; bi = i0; }        // ascending-index first-max
      if (m[1] > bv){ bv = m[1]; bi = i0 + 1; }
    }
#pragma unroll
    for (int off = 32; off > 0; off >>= 1){
      float ov = __shfl_down(bv, off);
      int oi = __shfl_down(bi, off);
      if (ov > bv || (ov == bv && oi < bi)){ bv = ov; bi = oi; }
    }
    int par = step & 1;
    if ((t & 63) == 0){ s_wv[par][t >> 6] = bv; s_wi[par][t >> 6] = bi; }
    __syncthreads();                               // only barrier per step
    float fv = s_wv[par][t & 7];
    int fi = s_wi[par][t & 7];
#pragma unroll
    for (int off = 1; off < 8; off <<= 1){
      float ov = __shfl_xor(fv, off);
      int oi = __shfl_xor(fi, off);
      if (ov > fv || (ov == fv && oi < fi)){ fv = ov; fi = oi; }
    }
    // fi is uniform across the wave: force SGPR so winner loads go scalar/uniform
    int fu = __builtin_amdgcn_readfirstlane(fi) & (N_ - 1);
    size_t wbase = (size_t)fu * 5;
    cx = cb[wbase+1]; cy = cb[wbase+2]; cz = cb[wbase+3]; ct = cb[wbase+4];
    if (t == 0) s_cent[step] = (f32x4){cx, cy, cz, ct};
  }
  __syncthreads();
  // fused stable time-sort + scatter (rank_scatter)
  if (t < M_){
    f32x4 c = s_cent[t];
    float w = c[3];
    int rank = 0;
    for (int j = 0; j < M_; j++){
      float tj = s_cent[j][3];
      if (tj < w || (tj == w && j < t)) rank++;    // stable argsort semantics
    }
    float* dst = cent_sorted + ((size_t)b * M_ + rank) * 4;
    dst[0]=c[0]; dst[1]=c[1]; dst[2]=c[2]; dst[3]=c[3];
    size_t co = (size_t)B_ * M_ * D_ + ((size_t)b * M_ + rank) * 4;
    if (co + 3 < out_elems){
      out[co+0]=c[0]; out[co+1]=c[1]; out[co+2]=c[2]; out[co+3]=c[3];
    }
    size_t mo = (size_t)B_ * M_ * D_ + (size_t)B_ * M_ * 4 + (size_t)b * M_ + t;
    if (mo < out_elems) out[mo] = 1.0f;            // mask = True -> 1.0f
  }
}

// ---------------- kNN: f32, np op order, stable-min extraction ----------------
#define KNT 512
#define KPT 32
__global__ __launch_bounds__(512) void knn_kernel(const float* __restrict__ coords,
                                                  const float* __restrict__ cent,
                                                  int* __restrict__ knn){
#pragma clang fp contract(off)
  int cm = blockIdx.x;
  int b = cm >> 7;
  const float* cb = coords + (size_t)b * N_ * 5;
  int t = threadIdx.x;
  float cx=cent[cm*4+0], cy=cent[cm*4+1], cz=cent[cm*4+2], ct=cent[cm*4+3];
  float dist[KPT];
#pragma unroll
  for (int j = 0; j < KPT; j++){
    size_t i = t + j * KNT;
    float dx=cb[i*5+1]-cx, dy=cb[i*5+2]-cy, dz=cb[i*5+3]-cz, dw=cb[i*5+4]-ct;
    float d = ((dx*dx + dy*dy) + dz*dz) + dw*dw;
    dist[j] = sqrtf(d);                            // IEEE f32 sqrt = np.sqrt(f32)
  }
  __shared__ float s_wv[8];
  __shared__ int s_wi[8];
  __shared__ int s_bi;
  for (int r = 0; r < K_; r++){
    float bv = 3e38f; int bi = 1 << 30;
#pragma unroll
    for (int j = 0; j < KPT; j++){
      int i = t + j * KNT;
      float v = dist[j];
      if (v < bv){ bv = v; bi = i; }               // first-min kept
    }
#pragma unroll
    for (int off = 32; off > 0; off >>= 1){
      float ov = __shfl_down(bv, off);
      int oi = __shfl_down(bi, off);
      if (ov < bv || (ov == bv && oi < bi)){ bv = ov; bi = oi; }
    }
    if ((t & 63) == 0){ s_wv[t >> 6] = bv; s_wi[t >> 6] = bi; }
    __syncthreads();
    if (t == 0){
      float fv = s_wv[0]; int fi = s_wi[0];
      for (int w = 1; w < 8; w++){
        float wv = s_wv[w]; int wi = s_wi[w];
        if (wv < fv || (wv == fv && wi < fi)){ fv = wv; fi = wi; }
      }
      s_bi = fi;
      knn[(size_t)cm * K_ + r] = fi & (N_ - 1);
    }
    __syncthreads();
    int wi = s_bi;
#pragma unroll
    for (int j = 0; j < KPT; j++){
      if (t + j * KNT == wi) dist[j] = 3e38f;
    }
  }
}

// ---------------- gather + layer0: 32 rows/block, W0/b0/features LDS-staged ----------------
__global__ __launch_bounds__(256) void gather_l0(const float* __restrict__ feat,
                                                 const int* __restrict__ knn,
                                                 const float* __restrict__ W0,
                                                 const float* __restrict__ b0,
                                                 u16* __restrict__ h1,
                                                 int rowBase){
  __shared__ float sW[F_][256];
  __shared__ float sb[256];
  __shared__ float sfa[32][F_];
  int t = threadIdx.x;
#pragma unroll
  for (int k = 0; k < F_; k++) sW[k][t] = W0[k * 256 + t];
  sb[t] = b0[t];
  if (t < 32 * F_){
    int r = t / F_, k = t % F_;
    int grow = rowBase + blockIdx.x * 32 + r;
    int bb = grow >> 11;                          // /(M*K)=2048
    int idx = knn[grow] & (N_ - 1);
    sfa[r][k] = feat[((size_t)bb * N_ + idx) * F_ + k];
  }
  __syncthreads();
#pragma unroll 4
  for (int r = 0; r < 32; r++){
    float acc = sb[t];
#pragma unroll
    for (int k = 0; k < F_; k++) acc = fmaf(sfa[r][k], sW[k][t], acc);
    int lrow = blockIdx.x * 32 + r;
    h1[(size_t)lrow * 256 + t] = f2bf(fmaxf(acc, 0.0f));
  }
}

// ---------------- bf16 MFMA GEMM (128x128 tile), WT[n][k] weights ----------------
template<int RELU, int OUTF32>
__global__ __launch_bounds__(256) void gemm_bf16(const u16* __restrict__ A,
                                                 const u16* __restrict__ WT,
                                                 const float* __restrict__ bias,
                                                 void* __restrict__ Cv,
                                                 int Kd, int Nd){
  __shared__ u16 As[128][40];
  __shared__ u16 Bs[128][40];
  const int t = threadIdx.x;
  const int bm = blockIdx.y << 7;
  const int bn = blockIdx.x << 7;
  const int wave = t >> 6;
  const int lane = t & 63;
  const int wm = (wave & 1) << 6;
  const int wn = (wave >> 1) << 6;
  const int lm = lane & 15;
  const int lk = (lane >> 4) << 3;
  f32x4 acc[4][4] = {};
  for (int k0 = 0; k0 < Kd; k0 += 32){
#pragma unroll
    for (int it = 0; it < 2; it++){
      int slot = t + (it << 8);
      int r = slot >> 2;
      int c = (slot & 3) << 3;
      short8 v = *(const short8*)(A + (size_t)(bm + r) * Kd + k0 + c);
      *(short8*)&As[r][c] = v;
      short8 w = *(const short8*)(WT + (size_t)(bn + r) * Kd + k0 + c);
      *(short8*)&Bs[r][c] = w;
    }
    __syncthreads();
    short8 af[4], bfr[4];
#pragma unroll
    for (int mt = 0; mt < 4; mt++) af[mt] = *(const short8*)&As[wm + (mt << 4) + lm][lk];
#pragma unroll
    for (int nt = 0; nt < 4; nt++) bfr[nt] = *(const short8*)&Bs[wn + (nt << 4) + lm][lk];
#pragma unroll
    for (int mt = 0; mt < 4; mt++)
#pragma unroll
      for (int nt = 0; nt < 4; nt++)
        acc[mt][nt] = __builtin_amdgcn_mfma_f32_16x16x32_bf16(af[mt], bfr[nt], acc[mt][nt], 0, 0, 0);
    __syncthreads();
  }
#pragma unroll
  for (int nt = 0; nt < 4; nt++){
    int n = bn + wn + (nt << 4) + lm;
    float bia = bias[n];
#pragma unroll
    for (int mt = 0; mt < 4; mt++){
#pragma unroll
      for (int r2 = 0; r2 < 4; r2++){
        int m = bm + wm + (mt << 4) + ((lane >> 4) << 2) + r2;
        float v = acc[mt][nt][r2] + bia;
        if (RELU) v = fmaxf(v, 0.0f);
        if (OUTF32) ((float*)Cv)[(size_t)m * Nd + n] = v;
        else        ((u16*)Cv)[(size_t)m * Nd + n] = f2bf(v);
      }
    }
  }
}

// ---------------- bf16 MFMA GEMM (64x64 tile), WT weights, token GEMMs ----------------
template<int RELU, int OUTF32>
__global__ __launch_bounds__(256) void gemm64(const u16* __restrict__ A,
                                              const u16* __restrict__ WT,
                                              const float* __restrict__ bias,
                                              void* __restrict__ Cv,
                                              int Kd, int Nd){
  __shared__ u16 As[64][40];
  __shared__ u16 Bs[64][40];
  const int t = threadIdx.x;
  const int bm = blockIdx.y << 6;
  const int bn = blockIdx.x << 6;
  const int wave = t >> 6;
  const int lane = t & 63;
  const int wm = (wave & 1) << 5;
  const int wn = (wave >> 1) << 5;
  const int lm = lane & 15;
  const int lk = (lane >> 4) << 3;
  f32x4 acc[2][2] = {};
  for (int k0 = 0; k0 < Kd; k0 += 32){
    {
      int r = t >> 2;
      int c = (t & 3) << 3;
      short8 v = *(const short8*)(A + (size_t)(bm + r) * Kd + k0 + c);
      *(short8*)&As[r][c] = v;
      short8 w = *(const short8*)(WT + (size_t)(bn + r) * Kd + k0 + c);
      *(short8*)&Bs[r][c] = w;
    }
    __syncthreads();
    short8 af[2], bfr[2];
#pragma unroll
    for (int mt = 0; mt < 2; mt++) af[mt] = *(const short8*)&As[wm + (mt << 4) + lm][lk];
#pragma unroll
    for (int nt = 0; nt < 2; nt++) bfr[nt] = *(const short8*)&Bs[wn + (nt << 4) + lm][lk];
#pragma unroll
    for (int mt = 0; mt < 2; mt++)
#pragma unroll
      for (int nt = 0; nt < 2; nt++)
        acc[mt][nt] = __builtin_amdgcn_mfma_f32_16x16x32_bf16(af[mt], bfr[nt], acc[mt][nt], 0, 0, 0);
    __syncthreads();
  }
#pragma unroll
  for (int nt = 0; nt < 2; nt++){
    int n = bn + wn + (nt << 4) + lm;
    float bia = bias[n];
#pragma unroll
    for (int mt = 0; mt < 2; mt++){
#pragma unroll
      for (int r2 = 0; r2 < 4; r2++){
        int m = bm + wm + (mt << 4) + ((lane >> 4) << 2) + r2;
        float v = acc[mt][nt][r2] + bia;
        if (RELU) v = fmaxf(v, 0.0f);
        if (OUTF32) ((float*)Cv)[(size_t)m * Nd + n] = v;
        else        ((u16*)Cv)[(size_t)m * Nd + n] = f2bf(v);
      }
    }
  }
}

// ---------------- GEMM + fused max-pool over 16-row groups, WT weights ----------------
__global__ __launch_bounds__(256) void gemm_pool(const u16* __restrict__ A,
                                                 const u16* __restrict__ WT,
                                                 const float* __restrict__ bias,
                                                 u16* __restrict__ pooled,
                                                 int Kd, int Nd, int groupBase){
  __shared__ u16 As[128][40];
  __shared__ u16 Bs[128][40];
  const int t = threadIdx.x;
  const int bm = blockIdx.y << 7;
  const int bn = blockIdx.x << 7;
  const int wave = t >> 6;
  const int lane = t & 63;
  const int wm = (wave & 1) << 6;
  const int wn = (wave >> 1) << 6;
  const int lm = lane & 15;
  const int lk = (lane >> 4) << 3;
  f32x4 acc[4][4] = {};
  for (int k0 = 0; k0 < Kd; k0 += 32){
#pragma unroll
    for (int it = 0; it < 2; it++){
      int slot = t + (it << 8);
      int r = slot >> 2;
      int c = (slot & 3) << 3;
      short8 v = *(const short8*)(A + (size_t)(bm + r) * Kd + k0 + c);
      *(short8*)&As[r][c] = v;
      short8 w = *(const short8*)(WT + (size_t)(bn + r) * Kd + k0 + c);
      *(short8*)&Bs[r][c] = w;
    }
    __syncthreads();
    short8 af[4], bfr[4];
#pragma unroll
    for (int mt = 0; mt < 4; mt++) af[mt] = *(const short8*)&As[wm + (mt << 4) + lm][lk];
#pragma unroll
    for (int nt = 0; nt < 4; nt++) bfr[nt] = *(const short8*)&Bs[wn + (nt << 4) + lm][lk];
#pragma unroll
    for (int mt = 0; mt < 4; mt++)
#pragma unroll
      for (int nt = 0; nt < 4; nt++)
        acc[mt][nt] = __builtin_amdgcn_mfma_f32_16x16x32_bf16(af[mt], bfr[nt], acc[mt][nt], 0, 0, 0);
    __syncthreads();
  }
  // each (mt) tile's 16 rows are exactly one pooling group
#pragma unroll
  for (int nt = 0; nt < 4; nt++){
    int n = bn + wn + (nt << 4) + lm;
    float bia = bias[n];
#pragma unroll
    for (int mt = 0; mt < 4; mt++){
      f32x4 a = acc[mt][nt];
      float v = fmaxf(fmaxf(a[0], a[1]), fmaxf(a[2], a[3]));
      v = fmaxf(v, __shfl_xor(v, 16));
      v = fmaxf(v, __shfl_xor(v, 32));
      if ((lane >> 4) == 0){
        int g = groupBase + (bm >> 4) + (wm >> 4) + mt;
        pooled[(size_t)g * Nd + n] = f2bf(v + bia);
      }
    }
  }
}

// ---------------- tier fallback (f32) ----------------
__global__ __launch_bounds__(256) void fill_diag(float* __restrict__ out, size_t out_elems){
  size_t i = (size_t)blockIdx.x * 256 + threadIdx.x;
  if (i >= out_elems) return;
  size_t maskStart = (size_t)B_ * M_ * D_ + (size_t)B_ * M_ * 4;
  out[i] = (i >= maskStart) ? 1.0f : 0.0f;
}

extern "C" void kernel_launch(void* const* d_in, const int* in_sizes, int n_in,
                              void* d_out, int out_size, void* d_ws, size_t ws_size,
                              hipStream_t stream){
  (void)in_sizes; (void)n_in;
  const float* coords   = (const float*)d_in[0];
  const float* features = (const float*)d_in[1];
  const float* W0 = (const float*)d_in[2];  const float* b0 = (const float*)d_in[3];
  const float* W1 = (const float*)d_in[4];  const float* b1 = (const float*)d_in[5];
  const float* W2 = (const float*)d_in[6];  const float* b2 = (const float*)d_in[7];
  const float* W3 = (const float*)d_in[8];  const float* b3 = (const float*)d_in[9];
  const float* Wn0 = (const float*)d_in[10]; const float* bn0 = (const float*)d_in[11];
  const float* Wn1 = (const float*)d_in[12]; const float* bn1 = (const float*)d_in[13];
  float* out = (float*)d_out;
  const size_t out_elems = (size_t)out_size;

  char* ws = (char*)d_ws;
  const size_t o_cntS = 0;            // 16,384
  const size_t o_knn  = 16384;        // 65,536 -> 81,920
  const size_t o_Wb   = 131072;       // 4,587,520 bf16 W1t..Wn1t (transposed)
  const size_t o_pool = 4718592;      // 1,572,864 bf16 [1024,768]
  const size_t o_t1   = 6291456;      // 1,572,864
  const size_t o_chunk= 7864320;      // regA (R*1536 B) + regB (R*1024 B)
  const int ROWS = B_ * M_ * K_;      // 16384

  int R = 16384;
  while (R > 128 && o_chunk + (size_t)R * 2560 > ws_size) R >>= 1;
  if (d_ws == nullptr || o_chunk + (size_t)R * 2560 > ws_size){
    fill_diag<<<(int)((out_elems + 255) / 256), 256, 0, stream>>>(out, out_elems);
    return;
  }

  float* cent_sorted = (float*)(ws + o_cntS);
  int*   knn         = (int*)(ws + o_knn);
  u16* Wb   = (u16*)(ws + o_Wb);
  u16* W1t  = Wb;               u16* W2t  = Wb + 131072;
  u16* W3t  = Wb + 524288;      u16* Wn0t = Wb + 1114112;
  u16* Wn1t = Wb + 1703936;
  u16* pooled = (u16*)(ws + o_pool);
  u16* t1     = (u16*)(ws + o_t1);
  u16* regA   = (u16*)(ws + o_chunk);                      // h1 [R,256] then h3 [R,768]
  u16* regB   = (u16*)(ws + o_chunk + (size_t)R * 1536);   // h2 [R,512]

  conv_all<<<560, 256, 0, stream>>>(W1, W2, W3, Wn0, Wn1, Wb);
  fps_kernel<<<B_, 512, 0, stream>>>(coords, cent_sorted, out, out_elems);
  knn_kernel<<<B_ * M_, KNT, 0, stream>>>(coords, cent_sorted, knn);

  for (int rowBase = 0; rowBase < ROWS; rowBase += R){
    gather_l0<<<R / 32, 256, 0, stream>>>(features, knn, W0, b0, regA, rowBase);
    gemm_bf16<1,0><<<dim3(4, R / 128), 256, 0, stream>>>(regA, W1t, b1, regB, 256, 512);
    gemm_bf16<1,0><<<dim3(6, R / 128), 256, 0, stream>>>(regB, W2t, b2, regA, 512, 768);
    gemm_pool<<<dim3(6, R / 128), 256, 0, stream>>>(regA, W3t, b3, pooled, 768, 768, rowBase >> 4);
  }

  gemm64<1,0><<<dim3(12, (B_ * M_) / 64), 256, 0, stream>>>(pooled, Wn0t, bn0, t1, 768, 768);
  gemm64<0,1><<<dim3(12, (B_ * M_) / 64), 256, 0, stream>>>(t1, Wn1t, bn1, out, 768, 768);
}

// Round 16
// 558.990 us; speedup vs baseline: 2.2534x; 1.0142x over previous
//
#include <hip/hip_runtime.h>

#define B_ 8
#define N_ 16384
#define F_ 6
#define M_ 128
#define K_ 16
#define D_ 768

typedef unsigned short u16;
typedef unsigned int u32;
typedef __attribute__((ext_vector_type(8))) short short8;
typedef __attribute__((ext_vector_type(4))) float f32x4;
typedef __attribute__((ext_vector_type(2))) float f32x2;

__device__ __forceinline__ u16 f2bf(float f){
  union { float f; u32 i; } v; v.f = f;
  u32 x = v.i;
  u32 r = x + 0x7FFFu + ((x >> 16) & 1u);
  return (u16)(r >> 16);
}

// async 16B global->LDS (dest = wave-uniform base + lane*16)
__device__ __forceinline__ void ld_g2l(const u16* g, u16* l){
  __builtin_amdgcn_global_load_lds((const __attribute__((address_space(1))) u32*)g,
                                   (__attribute__((address_space(3))) u32*)l, 16, 0, 0);
}

// ---------------- all weights f32 -> bf16 transposed [n][k], ONE kernel ----------------
__global__ __launch_bounds__(256) void conv_all(const float* __restrict__ W1,
                                                const float* __restrict__ W2,
                                                const float* __restrict__ W3,
                                                const float* __restrict__ Wn0,
                                                const float* __restrict__ Wn1,
                                                u16* __restrict__ Wb){
  __shared__ u16 tile[64][65];
  int blk = blockIdx.x;
  const float* W; u16* WT; int K, N, lb;
  if      (blk < 32)  { W = W1;  WT = Wb;           K = 256; N = 512; lb = blk; }
  else if (blk < 128) { W = W2;  WT = Wb + 131072;  K = 512; N = 768; lb = blk - 32; }
  else if (blk < 272) { W = W3;  WT = Wb + 524288;  K = 768; N = 768; lb = blk - 128; }
  else if (blk < 416) { W = Wn0; WT = Wb + 1114112; K = 768; N = 768; lb = blk - 272; }
  else                { W = Wn1; WT = Wb + 1703936; K = 768; N = 768; lb = blk - 416; }
  int tiles_n = N >> 6;
  int tk = lb / tiles_n, tn = lb % tiles_n;
  int k0 = tk << 6, n0 = tn << 6;
  int t = threadIdx.x;
#pragma unroll
  for (int q = 0; q < 16; q++){
    int idx = q * 256 + t;
    int kk = idx >> 6, nn = idx & 63;
    tile[kk][nn] = f2bf(W[(size_t)(k0 + kk) * N + n0 + nn]);
  }
  __syncthreads();
#pragma unroll
  for (int q = 0; q < 16; q++){
    int idx = q * 256 + t;
    int nn = idx >> 6, kk = idx & 63;
    WT[(size_t)(n0 + nn) * K + k0 + kk] = tile[kk][nn];
  }
}

// ---------------- FPS (round-14 best form): registers, 512 thr, 1 barrier/step ----------------
#define FPW 16
__global__ __launch_bounds__(512, 2) void fps_kernel(const float* __restrict__ coords,
                                                     float* __restrict__ cent){
#pragma clang fp contract(off)
  __shared__ float s_wv[2][8];
  __shared__ int s_wi[2][8];
  int b = blockIdx.x;
  int t = threadIdx.x;
  const float* cb = coords + (size_t)b * N_ * 5;
  f32x2 px[FPW], py[FPW], pz[FPW], pw[FPW], md[FPW];
#pragma unroll
  for (int j = 0; j < FPW; j++){
    int p = t + (j << 9);
    size_t i0 = (size_t)(2 * p) * 5;
    px[j] = (f32x2){cb[i0+1], cb[i0+6]};
    py[j] = (f32x2){cb[i0+2], cb[i0+7]};
    pz[j] = (f32x2){cb[i0+3], cb[i0+8]};
    pw[j] = (f32x2){cb[i0+4], cb[i0+9]};
    md[j] = (f32x2){1e30f, 1e30f};
  }
  float cx = cb[1], cy = cb[2], cz = cb[3], ct = cb[4];
  if (t == 0){
    float* c0 = cent + (size_t)b * M_ * 4;
    c0[0]=cx; c0[1]=cy; c0[2]=cz; c0[3]=ct;
  }
  for (int step = 1; step < M_; step++){
    f32x2 cx2 = (f32x2){cx, cx}, cy2 = (f32x2){cy, cy};
    f32x2 cz2 = (f32x2){cz, cz}, ct2 = (f32x2){ct, ct};
    float bv = -1.0f; int bi = 1 << 30;
#pragma unroll
    for (int j = 0; j < FPW; j++){
      f32x2 dX = px[j] - cx2;
      f32x2 dY = py[j] - cy2;
      f32x2 s = dX*dX + dY*dY;               // per-point numpy order (contract off)
      f32x2 dZ = pz[j] - cz2;
      s = s + dZ*dZ;
      f32x2 dW = pw[j] - ct2;
      s = s + dW*dW;
      f32x2 m = md[j];
      m[0] = (s[0] < m[0]) ? s[0] : m[0];
      m[1] = (s[1] < m[1]) ? s[1] : m[1];
      md[j] = m;
      int i0 = (t + (j << 9)) << 1;
      if (m[0] > bv){ bv = m[0]; bi = i0; }        // ascending-index first-max
      if (m[1] > bv){ bv = m[1]; bi = i0 + 1; }
    }
#pragma unroll
    for (int off = 32; off > 0; off >>= 1){
      float ov = __shfl_down(bv, off);
      int oi = __shfl_down(bi, off);
      if (ov > bv || (ov == bv && oi < bi)){ bv = ov; bi = oi; }
    }
    int par = step & 1;
    if ((t & 63) == 0){ s_wv[par][t >> 6] = bv; s_wi[par][t >> 6] = bi; }
    __syncthreads();                               // only barrier per step
    float fv = s_wv[par][t & 7];
    int fi = s_wi[par][t & 7];
#pragma unroll
    for (int off = 1; off < 8; off <<= 1){
      float ov = __shfl_xor(fv, off);
      int oi = __shfl_xor(fi, off);
      if (ov > fv || (ov == fv && oi < fi)){ fv = ov; fi = oi; }
    }
    fi &= (N_ - 1);
    size_t wbase = (size_t)fi * 5;
    cx = cb[wbase+1]; cy = cb[wbase+2]; cz = cb[wbase+3]; ct = cb[wbase+4];
    if (t == 0){
      float* cr = cent + ((size_t)b * M_ + step) * 4;
      cr[0]=cx; cr[1]=cy; cr[2]=cz; cr[3]=ct;
    }
  }
}

// ---------------- stable rank by centroid time; relabel early; f32 outputs ----------------
__global__ __launch_bounds__(128) void rank_scatter(const float* __restrict__ cent_fps,
                                                    float* __restrict__ cent_sorted,
                                                    float* __restrict__ out,
                                                    size_t out_elems){
  int b = blockIdx.x, m = threadIdx.x;
  __shared__ float tt[M_];
  const float* row = cent_fps + ((size_t)b * M_ + m) * 4;
  float x=row[0], y=row[1], z=row[2], w=row[3];
  tt[m] = w;
  __syncthreads();
  int rank = 0;
  for (int j = 0; j < M_; j++){
    float tj = tt[j];
    if (tj < w || (tj == w && j < m)) rank++;       // stable argsort semantics
  }
  float* dst = cent_sorted + ((size_t)b * M_ + rank) * 4;
  dst[0]=x; dst[1]=y; dst[2]=z; dst[3]=w;
  size_t co = (size_t)B_ * M_ * D_ + ((size_t)b * M_ + rank) * 4;
  if (co + 3 < out_elems){
    out[co+0]=x; out[co+1]=y; out[co+2]=z; out[co+3]=w;
  }
  size_t mo = (size_t)B_ * M_ * D_ + (size_t)B_ * M_ * 4 + (size_t)b * M_ + m;
  if (mo < out_elems) out[mo] = 1.0f;              // mask = True -> 1.0f
}

// ---------------- kNN: f32, np op order, stable-min extraction ----------------
#define KNT 512
#define KPT 32
__global__ __launch_bounds__(512) void knn_kernel(const float* __restrict__ coords,
                                                  const float* __restrict__ cent,
                                                  int* __restrict__ knn){
#pragma clang fp contract(off)
  int cm = blockIdx.x;
  int b = cm >> 7;
  const float* cb = coords + (size_t)b * N_ * 5;
  int t = threadIdx.x;
  float cx=cent[cm*4+0], cy=cent[cm*4+1], cz=cent[cm*4+2], ct=cent[cm*4+3];
  float dist[KPT];
#pragma unroll
  for (int j = 0; j < KPT; j++){
    size_t i = t + j * KNT;
    float dx=cb[i*5+1]-cx, dy=cb[i*5+2]-cy, dz=cb[i*5+3]-cz, dw=cb[i*5+4]-ct;
    float d = ((dx*dx + dy*dy) + dz*dz) + dw*dw;
    dist[j] = sqrtf(d);                            // IEEE f32 sqrt = np.sqrt(f32)
  }
  __shared__ float s_wv[8];
  __shared__ int s_wi[8];
  __shared__ int s_bi;
  for (int r = 0; r < K_; r++){
    float bv = 3e38f; int bi = 1 << 30;
#pragma unroll
    for (int j = 0; j < KPT; j++){
      int i = t + j * KNT;
      float v = dist[j];
      if (v < bv){ bv = v; bi = i; }               // first-min kept
    }
#pragma unroll
    for (int off = 32; off > 0; off >>= 1){
      float ov = __shfl_down(bv, off);
      int oi = __shfl_down(bi, off);
      if (ov < bv || (ov == bv && oi < bi)){ bv = ov; bi = oi; }
    }
    if ((t & 63) == 0){ s_wv[t >> 6] = bv; s_wi[t >> 6] = bi; }
    __syncthreads();
    if (t == 0){
      float fv = s_wv[0]; int fi = s_wi[0];
      for (int w = 1; w < 8; w++){
        float wv = s_wv[w]; int wi = s_wi[w];
        if (wv < fv || (wv == fv && wi < fi)){ fv = wv; fi = wi; }
      }
      s_bi = fi;
      knn[(size_t)cm * K_ + r] = fi & (N_ - 1);
    }
    __syncthreads();
    int wi = s_bi;
#pragma unroll
    for (int j = 0; j < KPT; j++){
      if (t + j * KNT == wi) dist[j] = 3e38f;
    }
  }
}

// ---------------- gather + layer0: 32 rows/block, W0/b0/features LDS-staged ----------------
__global__ __launch_bounds__(256) void gather_l0(const float* __restrict__ feat,
                                                 const int* __restrict__ knn,
                                                 const float* __restrict__ W0,
                                                 const float* __restrict__ b0,
                                                 u16* __restrict__ h1,
                                                 int rowBase){
  __shared__ float sW[F_][256];
  __shared__ float sb[256];
  __shared__ float sfa[32][F_];
  int t = threadIdx.x;
#pragma unroll
  for (int k = 0; k < F_; k++) sW[k][t] = W0[k * 256 + t];
  sb[t] = b0[t];
  if (t < 32 * F_){
    int r = t / F_, k = t % F_;
    int grow = rowBase + blockIdx.x * 32 + r;
    int bb = grow >> 11;                          // /(M*K)=2048
    int idx = knn[grow] & (N_ - 1);
    sfa[r][k] = feat[((size_t)bb * N_ + idx) * F_ + k];
  }
  __syncthreads();
#pragma unroll 4
  for (int r = 0; r < 32; r++){
    float acc = sb[t];
#pragma unroll
    for (int k = 0; k < F_; k++) acc = fmaf(sfa[r][k], sW[k][t], acc);
    int lrow = blockIdx.x * 32 + r;
    h1[(size_t)lrow * 256 + t] = f2bf(fmaxf(acc, 0.0f));
  }
}

// ---------------- bf16 MFMA GEMM (128x128), async global->LDS staging ----------------
// Unpadded [128][32] rows (64B): dest = wave-uniform base + lane*16 (m97 layout).
template<int RELU, int OUTF32>
__global__ __launch_bounds__(256) void gemm_bf16(const u16* __restrict__ A,
                                                 const u16* __restrict__ WT,
                                                 const float* __restrict__ bias,
                                                 void* __restrict__ Cv,
                                                 int Kd, int Nd){
  __shared__ u16 As[128][32];
  __shared__ u16 Bs[128][32];
  const int t = threadIdx.x;
  const int bm = blockIdx.y << 7;
  const int bn = blockIdx.x << 7;
  const int wave = t >> 6;
  const int lane = t & 63;
  const int wm = (wave & 1) << 6;
  const int wn = (wave >> 1) << 6;
  const int lm = lane & 15;
  const int lk = (lane >> 4) << 3;
  u16* AsF = &As[0][0];
  u16* BsF = &Bs[0][0];
  const int wbase = wave << 6;               // t - lane
  f32x4 acc[4][4] = {};
  for (int k0 = 0; k0 < Kd; k0 += 32){
#pragma unroll
    for (int it = 0; it < 2; it++){
      int slot = t + (it << 8);
      int r = slot >> 2;
      int c = (slot & 3) << 3;
      int dst = (wbase + (it << 8)) << 3;    // u16 elements; +lane*16B by HW
      ld_g2l(A  + (size_t)(bm + r) * Kd + k0 + c, AsF + dst);
      ld_g2l(WT + (size_t)(bn + r) * Kd + k0 + c, BsF + dst);
    }
    __syncthreads();
    short8 af[4], bfr[4];
#pragma unroll
    for (int mt = 0; mt < 4; mt++) af[mt] = *(const short8*)&As[wm + (mt << 4) + lm][lk];
#pragma unroll
    for (int nt = 0; nt < 4; nt++) bfr[nt] = *(const short8*)&Bs[wn + (nt << 4) + lm][lk];
#pragma unroll
    for (int mt = 0; mt < 4; mt++)
#pragma unroll
      for (int nt = 0; nt < 4; nt++)
        acc[mt][nt] = __builtin_amdgcn_mfma_f32_16x16x32_bf16(af[mt], bfr[nt], acc[mt][nt], 0, 0, 0);
    __syncthreads();
  }
#pragma unroll
  for (int nt = 0; nt < 4; nt++){
    int n = bn + wn + (nt << 4) + lm;
    float bia = bias[n];
#pragma unroll
    for (int mt = 0; mt < 4; mt++){
#pragma unroll
      for (int r2 = 0; r2 < 4; r2++){
        int m = bm + wm + (mt << 4) + ((lane >> 4) << 2) + r2;
        float v = acc[mt][nt][r2] + bia;
        if (RELU) v = fmaxf(v, 0.0f);
        if (OUTF32) ((float*)Cv)[(size_t)m * Nd + n] = v;
        else        ((u16*)Cv)[(size_t)m * Nd + n] = f2bf(v);
      }
    }
  }
}

// ---------------- bf16 MFMA GEMM (64x64), async staging, token GEMMs ----------------
template<int RELU, int OUTF32>
__global__ __launch_bounds__(256) void gemm64(const u16* __restrict__ A,
                                              const u16* __restrict__ WT,
                                              const float* __restrict__ bias,
                                              void* __restrict__ Cv,
                                              int Kd, int Nd){
  __shared__ u16 As[64][32];
  __shared__ u16 Bs[64][32];
  const int t = threadIdx.x;
  const int bm = blockIdx.y << 6;
  const int bn = blockIdx.x << 6;
  const int wave = t >> 6;
  const int lane = t & 63;
  const int wm = (wave & 1) << 5;
  const int wn = (wave >> 1) << 5;
  const int lm = lane & 15;
  const int lk = (lane >> 4) << 3;
  u16* AsF = &As[0][0];
  u16* BsF = &Bs[0][0];
  const int wbase = wave << 6;
  f32x4 acc[2][2] = {};
  for (int k0 = 0; k0 < Kd; k0 += 32){
    {
      int r = t >> 2;
      int c = (t & 3) << 3;
      int dst = wbase << 3;
      ld_g2l(A  + (size_t)(bm + r) * Kd + k0 + c, AsF + dst);
      ld_g2l(WT + (size_t)(bn + r) * Kd + k0 + c, BsF + dst);
    }
    __syncthreads();
    short8 af[2], bfr[2];
#pragma unroll
    for (int mt = 0; mt < 2; mt++) af[mt] = *(const short8*)&As[wm + (mt << 4) + lm][lk];
#pragma unroll
    for (int nt = 0; nt < 2; nt++) bfr[nt] = *(const short8*)&Bs[wn + (nt << 4) + lm][lk];
#pragma unroll
    for (int mt = 0; mt < 2; mt++)
#pragma unroll
      for (int nt = 0; nt < 2; nt++)
        acc[mt][nt] = __builtin_amdgcn_mfma_f32_16x16x32_bf16(af[mt], bfr[nt], acc[mt][nt], 0, 0, 0);
    __syncthreads();
  }
#pragma unroll
  for (int nt = 0; nt < 2; nt++){
    int n = bn + wn + (nt << 4) + lm;
    float bia = bias[n];
#pragma unroll
    for (int mt = 0; mt < 2; mt++){
#pragma unroll
      for (int r2 = 0; r2 < 4; r2++){
        int m = bm + wm + (mt << 4) + ((lane >> 4) << 2) + r2;
        float v = acc[mt][nt][r2] + bia;
        if (RELU) v = fmaxf(v, 0.0f);
        if (OUTF32) ((float*)Cv)[(size_t)m * Nd + n] = v;
        else        ((u16*)Cv)[(size_t)m * Nd + n] = f2bf(v);
      }
    }
  }
}

// ---------------- GEMM + fused max-pool (128x128), async staging ----------------
__global__ __launch_bounds__(256) void gemm_pool(const u16* __restrict__ A,
                                                 const u16* __restrict__ WT,
                                                 const float* __restrict__ bias,
                                                 u16* __restrict__ pooled,
                                                 int Kd, int Nd, int groupBase){
  __shared__ u16 As[128][32];
  __shared__ u16 Bs[128][32];
  const int t = threadIdx.x;
  const int bm = blockIdx.y << 7;
  const int bn = blockIdx.x << 7;
  const int wave = t >> 6;
  const int lane = t & 63;
  const int wm = (wave & 1) << 6;
  const int wn = (wave >> 1) << 6;
  const int lm = lane & 15;
  const int lk = (lane >> 4) << 3;
  u16* AsF = &As[0][0];
  u16* BsF = &Bs[0][0];
  const int wbase = wave << 6;
  f32x4 acc[4][4] = {};
  for (int k0 = 0; k0 < Kd; k0 += 32){
#pragma unroll
    for (int it = 0; it < 2; it++){
      int slot = t + (it << 8);
      int r = slot >> 2;
      int c = (slot & 3) << 3;
      int dst = (wbase + (it << 8)) << 3;
      ld_g2l(A  + (size_t)(bm + r) * Kd + k0 + c, AsF + dst);
      ld_g2l(WT + (size_t)(bn + r) * Kd + k0 + c, BsF + dst);
    }
    __syncthreads();
    short8 af[4], bfr[4];
#pragma unroll
    for (int mt = 0; mt < 4; mt++) af[mt] = *(const short8*)&As[wm + (mt << 4) + lm][lk];
#pragma unroll
    for (int nt = 0; nt < 4; nt++) bfr[nt] = *(const short8*)&Bs[wn + (nt << 4) + lm][lk];
#pragma unroll
    for (int mt = 0; mt < 4; mt++)
#pragma unroll
      for (int nt = 0; nt < 4; nt++)
        acc[mt][nt] = __builtin_amdgcn_mfma_f32_16x16x32_bf16(af[mt], bfr[nt], acc[mt][nt], 0, 0, 0);
    __syncthreads();
  }
  // each (mt) tile's 16 rows are exactly one pooling group
#pragma unroll
  for (int nt = 0; nt < 4; nt++){
    int n = bn + wn + (nt << 4) + lm;
    float bia = bias[n];
#pragma unroll
    for (int mt = 0; mt < 4; mt++){
      f32x4 a = acc[mt][nt];
      float v = fmaxf(fmaxf(a[0], a[1]), fmaxf(a[2], a[3]));
      v = fmaxf(v, __shfl_xor(v, 16));
      v = fmaxf(v, __shfl_xor(v, 32));
      if ((lane >> 4) == 0){
        int g = groupBase + (bm >> 4) + (wm >> 4) + mt;
        pooled[(size_t)g * Nd + n] = f2bf(v + bia);
      }
    }
  }
}

// ---------------- tier fallback (f32) ----------------
__global__ __launch_bounds__(256) void fill_diag(float* __restrict__ out, size_t out_elems){
  size_t i = (size_t)blockIdx.x * 256 + threadIdx.x;
  if (i >= out_elems) return;
  size_t maskStart = (size_t)B_ * M_ * D_ + (size_t)B_ * M_ * 4;
  out[i] = (i >= maskStart) ? 1.0f : 0.0f;
}

extern "C" void kernel_launch(void* const* d_in, const int* in_sizes, int n_in,
                              void* d_out, int out_size, void* d_ws, size_t ws_size,
                              hipStream_t stream){
  (void)in_sizes; (void)n_in;
  const float* coords   = (const float*)d_in[0];
  const float* features = (const float*)d_in[1];
  const float* W0 = (const float*)d_in[2];  const float* b0 = (const float*)d_in[3];
  const float* W1 = (const float*)d_in[4];  const float* b1 = (const float*)d_in[5];
  const float* W2 = (const float*)d_in[6];  const float* b2 = (const float*)d_in[7];
  const float* W3 = (const float*)d_in[8];  const float* b3 = (const float*)d_in[9];
  const float* Wn0 = (const float*)d_in[10]; const float* bn0 = (const float*)d_in[11];
  const float* Wn1 = (const float*)d_in[12]; const float* bn1 = (const float*)d_in[13];
  float* out = (float*)d_out;
  const size_t out_elems = (size_t)out_size;

  char* ws = (char*)d_ws;
  const size_t o_cent = 0;            // 16,384 (FPS order)
  const size_t o_cntS = 16384;        // 16,384 (time order)
  const size_t o_knn  = 32768;        // 65,536 -> 98,304
  const size_t o_Wb   = 131072;       // 4,587,520 bf16 W1t..Wn1t (transposed)
  const size_t o_pool = 4718592;      // 1,572,864 bf16 [1024,768]
  const size_t o_t1   = 6291456;      // 1,572,864
  const size_t o_chunk= 7864320;      // regA (R*1536 B) + regB (R*1024 B)
  const int ROWS = B_ * M_ * K_;      // 16384

  int R = 16384;
  while (R > 128 && o_chunk + (size_t)R * 2560 > ws_size) R >>= 1;
  if (d_ws == nullptr || o_chunk + (size_t)R * 2560 > ws_size){
    fill_diag<<<(int)((out_elems + 255) / 256), 256, 0, stream>>>(out, out_elems);
    return;
  }

  float* cent_fps    = (float*)(ws + o_cent);
  float* cent_sorted = (float*)(ws + o_cntS);
  int*   knn         = (int*)(ws + o_knn);
  u16* Wb   = (u16*)(ws + o_Wb);
  u16* W1t  = Wb;               u16* W2t  = Wb + 131072;
  u16* W3t  = Wb + 524288;      u16* Wn0t = Wb + 1114112;
  u16* Wn1t = Wb + 1703936;
  u16* pooled = (u16*)(ws + o_pool);
  u16* t1     = (u16*)(ws + o_t1);
  u16* regA   = (u16*)(ws + o_chunk);                      // h1 [R,256] then h3 [R,768]
  u16* regB   = (u16*)(ws + o_chunk + (size_t)R * 1536);   // h2 [R,512]

  conv_all<<<560, 256, 0, stream>>>(W1, W2, W3, Wn0, Wn1, Wb);
  fps_kernel<<<B_, 512, 0, stream>>>(coords, cent_fps);
  rank_scatter<<<B_, 128, 0, stream>>>(cent_fps, cent_sorted, out, out_elems);
  knn_kernel<<<B_ * M_, KNT, 0, stream>>>(coords, cent_sorted, knn);

  for (int rowBase = 0; rowBase < ROWS; rowBase += R){
    gather_l0<<<R / 32, 256, 0, stream>>>(features, knn, W0, b0, regA, rowBase);
    gemm_bf16<1,0><<<dim3(4, R / 128), 256, 0, stream>>>(regA, W1t, b1, regB, 256, 512);
    gemm_bf16<1,0><<<dim3(6, R / 128), 256, 0, stream>>>(regB, W2t, b2, regA, 512, 768);
    gemm_pool<<<dim3(6, R / 128), 256, 0, stream>>>(regA, W3t, b3, pooled, 768, 768, rowBase >> 4);
  }

  gemm64<1,0><<<dim3(12, (B_ * M_) / 64), 256, 0, stream>>>(pooled, Wn0t, bn0, t1, 768, 768);
  gemm64<0,1><<<dim3(12, (B_ * M_) / 64), 256, 0, stream>>>(t1, Wn1t, bn1, out, 768, 768);
}